// Round 1
// baseline (1612.427 us; speedup 1.0000x reference)
//
#include <hip/hip_runtime.h>
#include <math.h>

#define NH 8
#define NC 16
#define HC 128

__device__ __forceinline__ float eluf(float x) { return x > 0.f ? x : expm1f(x); }
__device__ __forceinline__ float splusf(float x) { return fmaxf(x, 0.f) + log1pf(expf(-fabsf(x))); }

// ---------------- CSR build ----------------
__global__ void count_kernel(const int* __restrict__ ei, int* __restrict__ cnt, int E, int E2) {
    int e = blockIdx.x * blockDim.x + threadIdx.x;
    if (e >= E2) return;
    int col = (e < E) ? ei[E + e] : (e - E);
    atomicAdd(&cnt[col], 1);
}

__global__ void scan1_kernel(const int* __restrict__ counts, int* __restrict__ ptr,
                             int* __restrict__ partials, int n) {
    __shared__ int tmp[256];
    int t = threadIdx.x;
    int i = blockIdx.x * 256 + t;
    int v = (i < n) ? counts[i] : 0;
    tmp[t] = v;
    __syncthreads();
    for (int off = 1; off < 256; off <<= 1) {
        int add = (t >= off) ? tmp[t - off] : 0;
        __syncthreads();
        tmp[t] += add;
        __syncthreads();
    }
    if (i < n) ptr[i] = tmp[t] - v;            // block-local exclusive
    if (t == 255) partials[blockIdx.x] = tmp[255];
}

__global__ void scan2_kernel(int* __restrict__ partials, int nb) {
    __shared__ int tmp[256];
    int t = threadIdx.x;
    int v = (t < nb) ? partials[t] : 0;
    tmp[t] = v;
    __syncthreads();
    for (int off = 1; off < 256; off <<= 1) {
        int add = (t >= off) ? tmp[t - off] : 0;
        __syncthreads();
        tmp[t] += add;
        __syncthreads();
    }
    if (t < nb) partials[t] = tmp[t] - v;      // exclusive
}

__global__ void scan3_kernel(int* __restrict__ ptr, const int* __restrict__ partials,
                             int n, int total) {
    int i = blockIdx.x * 256 + threadIdx.x;
    if (i < n) ptr[i] += partials[blockIdx.x];
    if (i == 0) ptr[n] = total;
}

__global__ void fill_kernel(const int* __restrict__ ei, const int* __restrict__ ptr,
                            int* __restrict__ cursor, int* __restrict__ src, int E, int E2) {
    int e = blockIdx.x * blockDim.x + threadIdx.x;
    if (e >= E2) return;
    int col, row;
    if (e < E) { row = ei[e]; col = ei[E + e]; }
    else       { row = e - E; col = e - E; }
    int pos = ptr[col] + atomicAdd(&cursor[col], 1);
    src[pos] = row;
}

// ---------------- fp32 GEMM: out[M x 128] = act(A[M x K] @ W[K x 128] + b) ----------------
template<int K, bool ELU_OUT>
__global__ __launch_bounds__(256)
void mlp_gemm(const float* __restrict__ A, const float* __restrict__ W,
              const float* __restrict__ bias, float* __restrict__ out, int M) {
    __shared__ float As[16][132];   // [k][m], padded
    __shared__ float Ws[16][128];   // [k][n]
    const int tid = threadIdx.x;
    const int m0 = blockIdx.x * 128;
    const int tm = tid >> 4;        // 0..15
    const int tn = tid & 15;        // 0..15
    float acc[8][8];
#pragma unroll
    for (int i = 0; i < 8; ++i)
#pragma unroll
        for (int j = 0; j < 8; ++j) acc[i][j] = 0.f;

    const int ra = tid >> 1;            // 0..127 (A tile row)
    const int ha = (tid & 1) * 8;       // k-offset half
    const int rw = tid >> 4;            // 0..15 (W tile row)
    const int cw = (tid & 15) * 8;      // W col

    for (int k0 = 0; k0 < K; k0 += 16) {
        float4 a0 = make_float4(0.f, 0.f, 0.f, 0.f), a1 = a0;
        int garow = m0 + ra;
        if (garow < M) {
            const float* ap = A + (size_t)garow * K + k0 + ha;
            a0 = *(const float4*)(ap);
            a1 = *(const float4*)(ap + 4);
        }
        const float* wp = W + (size_t)(k0 + rw) * 128 + cw;
        float4 w0 = *(const float4*)(wp);
        float4 w1 = *(const float4*)(wp + 4);
        __syncthreads();
        As[ha + 0][ra] = a0.x; As[ha + 1][ra] = a0.y; As[ha + 2][ra] = a0.z; As[ha + 3][ra] = a0.w;
        As[ha + 4][ra] = a1.x; As[ha + 5][ra] = a1.y; As[ha + 6][ra] = a1.z; As[ha + 7][ra] = a1.w;
        *(float4*)&Ws[rw][cw]     = w0;
        *(float4*)&Ws[rw][cw + 4] = w1;
        __syncthreads();
#pragma unroll
        for (int kk = 0; kk < 16; ++kk) {
            float ar[8], wr[8];
            *(float4*)&ar[0] = *(const float4*)&As[kk][tm * 8];
            *(float4*)&ar[4] = *(const float4*)&As[kk][tm * 8 + 4];
            *(float4*)&wr[0] = *(const float4*)&Ws[kk][tn * 8];
            *(float4*)&wr[4] = *(const float4*)&Ws[kk][tn * 8 + 4];
#pragma unroll
            for (int i = 0; i < 8; ++i)
#pragma unroll
                for (int j = 0; j < 8; ++j)
                    acc[i][j] = fmaf(ar[i], wr[j], acc[i][j]);
        }
    }
#pragma unroll
    for (int i = 0; i < 8; ++i) {
        int r = m0 + tm * 8 + i;
        if (r < M) {
            float* op = out + (size_t)r * 128 + tn * 8;
#pragma unroll
            for (int j = 0; j < 8; ++j) {
                float v = acc[i][j] + bias[tn * 8 + j];
                if (ELU_OUT) v = eluf(v);
                op[j] = v;
            }
        }
    }
}

// ---------------- hop-0 attention: z = h * g ----------------
__global__ void hop0_kernel(const float* __restrict__ h, const float* __restrict__ att0,
                            const float* __restrict__ hb, float* __restrict__ z, int n) {
    int id = blockIdx.x * blockDim.x + threadIdx.x;
    if (id >= n * NH) return;
    int node = id >> 3, hd = id & 7;
    const float* hp = h + (size_t)node * HC + hd * NC;
    float v[16];
    *(float4*)&v[0]  = *(const float4*)(hp);
    *(float4*)&v[4]  = *(const float4*)(hp + 4);
    *(float4*)&v[8]  = *(const float4*)(hp + 8);
    *(float4*)&v[12] = *(const float4*)(hp + 12);
    float g = hb[hd];
#pragma unroll
    for (int c = 0; c < 16; ++c) g += att0[hd * 16 + c] * eluf(v[c]);
    float* zp = z + (size_t)node * HC + hd * NC;
    float o[16];
#pragma unroll
    for (int c = 0; c < 16; ++c) o[c] = v[c] * g;
    *(float4*)(zp)      = *(float4*)&o[0];
    *(float4*)(zp + 4)  = *(float4*)&o[4];
    *(float4*)(zp + 8)  = *(float4*)&o[8];
    *(float4*)(zp + 12) = *(float4*)&o[12];
}

// ---------------- pass A: edge attention + degree (one wave per node) ----------------
__global__ __launch_bounds__(256)
void passA_kernel(const float* __restrict__ z, const int* __restrict__ ptr,
                  const int* __restrict__ src, const float* __restrict__ att,
                  float decay, float* __restrict__ a_e, float* __restrict__ deg, int n) {
    int wave = (int)((blockIdx.x * (unsigned)blockDim.x + threadIdx.x) >> 6);
    if (wave >= n) return;
    int lane = threadIdx.x & 63;
    int hd = lane >> 3, c2 = lane & 7;
    int i = wave;
    const float* zi_p = z + (size_t)i * HC + hd * NC + c2 * 2;
    float2 zi = *(const float2*)zi_p;
    zi.x *= decay; zi.y *= decay;
    float2 av = *(const float2*)(att + hd * NC + c2 * 2);
    int s0 = ptr[i], s1 = ptr[i + 1];
    float dacc = 0.f;
    for (int s = s0; s < s1; ++s) {
        int j = src[s];
        float2 zj = *(const float2*)(z + (size_t)j * HC + hd * NC + c2 * 2);
        float vx = eluf(zi.x + zj.x * decay);
        float vy = eluf(zi.y + zj.y * decay);
        float p = av.x * vx + av.y * vy;
        p += __shfl_xor(p, 1);
        p += __shfl_xor(p, 2);
        p += __shfl_xor(p, 4);
        if (c2 == 0) {
            float aval = splusf(p) + 1e-6f;
            a_e[(size_t)s * NH + hd] = aval;
            dacc += aval;
        }
    }
    if (c2 == 0) deg[(size_t)i * NH + hd] = dacc;
}

__global__ void dinv_kernel(float* __restrict__ deg, int total) {
    int id = blockIdx.x * blockDim.x + threadIdx.x;
    if (id >= total) return;
    float d = deg[id];
    deg[id] = (d > 0.f) ? (1.f / sqrtf(d)) : 0.f;
}

// ---------------- pass B: propagate + hop attention + z update (one block per node) ----
__global__ __launch_bounds__(128)
void passB_kernel(const float* __restrict__ h_in, float* __restrict__ z,
                  const int* __restrict__ ptr, const int* __restrict__ src,
                  const float* __restrict__ a_e, const float* __restrict__ dinv,
                  const float* __restrict__ hatt, const float* __restrict__ hb,
                  float decay, float* __restrict__ h_out, int n) {
    int i = blockIdx.x;
    if (i >= n) return;
    int tid = threadIdx.x;
    int hd = tid >> 4, c = tid & 15;
    float di = dinv[(size_t)i * NH + hd];
    int s0 = ptr[i], s1 = ptr[i + 1];
    float acc = 0.f;
    for (int s = s0; s < s1; ++s) {
        int j = src[s];
        float w = a_e[(size_t)s * NH + hd] * dinv[(size_t)j * NH + hd];
        acc = fmaf(w, h_in[(size_t)j * HC + tid], acc);
    }
    float hn = di * acc;
    h_out[(size_t)i * HC + tid] = hn;
    float zv = z[(size_t)i * HC + tid];
    float zs = zv * decay;
    float p = hatt[hd * 32 + c] * eluf(hn) + hatt[hd * 32 + 16 + c] * eluf(zs);
    p += __shfl_xor(p, 1);
    p += __shfl_xor(p, 2);
    p += __shfl_xor(p, 4);
    p += __shfl_xor(p, 8);
    float g = p + hb[hd];
    z[(size_t)i * HC + tid] = zv + hn * g;
}

// ---------------- output GEMM: out[M x 40] = elu(z)[M x 128] @ Wout + bout --------------
__global__ __launch_bounds__(256)
void gout_kernel(const float* __restrict__ z, const float* __restrict__ W,
                 const float* __restrict__ bias, float* __restrict__ out, int M) {
    __shared__ float zs[128 * 65];   // [k][r], stride 65
    __shared__ float ws[128 * 40];   // [k][n]
    const int tid = threadIdx.x;
    const int r0 = blockIdx.x * 64;
    for (int idx = tid; idx < 128 * 40; idx += 256) ws[idx] = W[idx];
    const int r = tid >> 2;   // 0..63
    const int q = tid & 3;    // 0..3
    {
        int grow = r0 + r;
#pragma unroll
        for (int t = 0; t < 8; ++t) {
            int k = q * 4 + t * 16;
            float4 v = make_float4(0.f, 0.f, 0.f, 0.f);
            if (grow < M) v = *(const float4*)(z + (size_t)grow * HC + k);
            zs[(k + 0) * 65 + r] = eluf(v.x);
            zs[(k + 1) * 65 + r] = eluf(v.y);
            zs[(k + 2) * 65 + r] = eluf(v.z);
            zs[(k + 3) * 65 + r] = eluf(v.w);
        }
    }
    __syncthreads();
    float acc[10];
#pragma unroll
    for (int j = 0; j < 10; ++j) acc[j] = bias[q * 10 + j];
    for (int k = 0; k < 128; ++k) {
        float zk = zs[k * 65 + r];
#pragma unroll
        for (int j = 0; j < 10; ++j)
            acc[j] = fmaf(zk, ws[k * 40 + q * 10 + j], acc[j]);
    }
    int grow = r0 + r;
    if (grow < M) {
        float* op = out + (size_t)grow * 40 + q * 10;
#pragma unroll
        for (int j = 0; j < 10; ++j) op[j] = acc[j];
    }
}

extern "C" void kernel_launch(void* const* d_in, const int* in_sizes, int n_in,
                              void* d_out, int out_size, void* d_ws, size_t ws_size,
                              hipStream_t stream) {
    (void)n_in; (void)out_size; (void)ws_size;
    const float* x    = (const float*)d_in[0];
    const int*   ei   = (const int*)d_in[1];
    const float* W0   = (const float*)d_in[2];
    const float* b0   = (const float*)d_in[3];
    const float* W1   = (const float*)d_in[4];
    const float* b1   = (const float*)d_in[5];
    const float* Wout = (const float*)d_in[6];
    const float* bout = (const float*)d_in[7];
    const float* att0 = (const float*)d_in[8];
    const float* hatts= (const float*)d_in[9];
    const float* atts = (const float*)d_in[10];
    const float* hb   = (const float*)d_in[11];
    float* out = (float*)d_out;

    const int N  = in_sizes[0] / 256;
    const int E  = in_sizes[1] / 2;
    const int E2 = E + N;

    char* p = (char*)d_ws;
    auto carve = [&](size_t bytes) -> char* {
        char* r = p;
        p += (bytes + 255) & ~(size_t)255;
        return r;
    };
    float* h1      = (float*)carve((size_t)N * HC * 4);
    float* hbuf    = (float*)carve((size_t)N * HC * 4);
    float* zbuf    = (float*)carve((size_t)N * HC * 4);
    float* a_e     = (float*)carve((size_t)E2 * NH * 4);
    float* degb    = (float*)carve((size_t)N * NH * 4);
    int* csr_ptr   = (int*)carve((size_t)(N + 1) * 4);
    int* csr_src   = (int*)carve((size_t)E2 * 4);
    int* cursor    = (int*)carve((size_t)N * 4);
    int* partials  = (int*)carve(1024 * 4);

    float decay[5];
    for (int k = 0; k <= 4; ++k) decay[k] = (float)log(1.0 / (k + 1) + 1.0 + 1e-6);

    // ---- CSR build (by destination col) ----
    hipMemsetAsync(cursor, 0, (size_t)N * 4, stream);
    int eb = (E2 + 255) / 256;
    int nb = (N + 255) / 256;
    count_kernel<<<eb, 256, 0, stream>>>(ei, cursor, E, E2);
    scan1_kernel<<<nb, 256, 0, stream>>>(cursor, csr_ptr, partials, N);
    scan2_kernel<<<1, 256, 0, stream>>>(partials, nb);
    scan3_kernel<<<nb, 256, 0, stream>>>(csr_ptr, partials, N, E2);
    hipMemsetAsync(cursor, 0, (size_t)N * 4, stream);
    fill_kernel<<<eb, 256, 0, stream>>>(ei, csr_ptr, cursor, csr_src, E, E2);

    // ---- MLP ----
    int gb = (N + 127) / 128;
    mlp_gemm<256, true ><<<gb, 256, 0, stream>>>(x,  W0, b0, h1,   N);
    mlp_gemm<128, false><<<gb, 256, 0, stream>>>(h1, W1, b1, hbuf, N);

    // ---- hop 0 ----
    hop0_kernel<<<(N * NH + 255) / 256, 256, 0, stream>>>(hbuf, att0, hb, zbuf, N);

    // ---- hops 1..4 ----
    float* hin  = hbuf;
    float* hout = h1;
    for (int k = 1; k <= 4; ++k) {
        passA_kernel<<<(N + 3) / 4, 256, 0, stream>>>(zbuf, csr_ptr, csr_src,
                                                      atts + (size_t)(k - 1) * NH * NC,
                                                      decay[k - 1], a_e, degb, N);
        dinv_kernel<<<(N * NH + 255) / 256, 256, 0, stream>>>(degb, N * NH);
        passB_kernel<<<N, 128, 0, stream>>>(hin, zbuf, csr_ptr, csr_src, a_e, degb,
                                            hatts + (size_t)(k - 1) * NH * 32,
                                            hb + (size_t)k * NH, decay[k - 1], hout, N);
        float* t = hin; hin = hout; hout = t;
    }

    // ---- classifier ----
    gout_kernel<<<(N + 63) / 64, 256, 0, stream>>>(zbuf, Wout, bout, out, N);
}

// Round 2
// 974.834 us; speedup vs baseline: 1.6541x; 1.6541x over previous
//
#include <hip/hip_runtime.h>
#include <math.h>

#define NH 8
#define NC 16
#define HC 128

// Fast transcendentals: v_exp_f32 / v_log_f32 hardware paths (~1 ulp),
// vs libm expm1f/log1pf (~15+ VALU instrs each). passA is VALU-issue bound.
__device__ __forceinline__ float eluf(float x) { return x > 0.f ? x : __expf(x) - 1.f; }
__device__ __forceinline__ float splusf(float x) { return fmaxf(x, 0.f) + __logf(1.f + __expf(-fabsf(x))); }

// ---------------- CSR build ----------------
__global__ void count_kernel(const int* __restrict__ ei, int* __restrict__ cnt, int E, int E2) {
    int e = blockIdx.x * blockDim.x + threadIdx.x;
    if (e >= E2) return;
    int col = (e < E) ? ei[E + e] : (e - E);
    atomicAdd(&cnt[col], 1);
}

__global__ void scan1_kernel(const int* __restrict__ counts, int* __restrict__ ptr,
                             int* __restrict__ partials, int n) {
    __shared__ int tmp[256];
    int t = threadIdx.x;
    int i = blockIdx.x * 256 + t;
    int v = (i < n) ? counts[i] : 0;
    tmp[t] = v;
    __syncthreads();
    for (int off = 1; off < 256; off <<= 1) {
        int add = (t >= off) ? tmp[t - off] : 0;
        __syncthreads();
        tmp[t] += add;
        __syncthreads();
    }
    if (i < n) ptr[i] = tmp[t] - v;            // block-local exclusive
    if (t == 255) partials[blockIdx.x] = tmp[255];
}

__global__ void scan2_kernel(int* __restrict__ partials, int nb) {
    __shared__ int tmp[256];
    int t = threadIdx.x;
    int v = (t < nb) ? partials[t] : 0;
    tmp[t] = v;
    __syncthreads();
    for (int off = 1; off < 256; off <<= 1) {
        int add = (t >= off) ? tmp[t - off] : 0;
        __syncthreads();
        tmp[t] += add;
        __syncthreads();
    }
    if (t < nb) partials[t] = tmp[t] - v;      // exclusive
}

__global__ void scan3_kernel(int* __restrict__ ptr, const int* __restrict__ partials,
                             int n, int total) {
    int i = blockIdx.x * 256 + threadIdx.x;
    if (i < n) ptr[i] += partials[blockIdx.x];
    if (i == 0) ptr[n] = total;
}

__global__ void fill_kernel(const int* __restrict__ ei, const int* __restrict__ ptr,
                            int* __restrict__ cursor, int* __restrict__ src, int E, int E2) {
    int e = blockIdx.x * blockDim.x + threadIdx.x;
    if (e >= E2) return;
    int col, row;
    if (e < E) { row = ei[e]; col = ei[E + e]; }
    else       { row = e - E; col = e - E; }
    int pos = ptr[col] + atomicAdd(&cursor[col], 1);
    src[pos] = row;
}

// ---------------- fp32 GEMM: out[M x 128] = act(A[M x K] @ W[K x 128] + b) ----------------
template<int K, bool ELU_OUT>
__global__ __launch_bounds__(256)
void mlp_gemm(const float* __restrict__ A, const float* __restrict__ W,
              const float* __restrict__ bias, float* __restrict__ out, int M) {
    __shared__ float As[16][132];   // [k][m], padded
    __shared__ float Ws[16][128];   // [k][n]
    const int tid = threadIdx.x;
    const int m0 = blockIdx.x * 128;
    const int tm = tid >> 4;        // 0..15
    const int tn = tid & 15;        // 0..15
    float acc[8][8];
#pragma unroll
    for (int i = 0; i < 8; ++i)
#pragma unroll
        for (int j = 0; j < 8; ++j) acc[i][j] = 0.f;

    const int ra = tid >> 1;            // 0..127 (A tile row)
    const int ha = (tid & 1) * 8;       // k-offset half
    const int rw = tid >> 4;            // 0..15 (W tile row)
    const int cw = (tid & 15) * 8;      // W col

    for (int k0 = 0; k0 < K; k0 += 16) {
        float4 a0 = make_float4(0.f, 0.f, 0.f, 0.f), a1 = a0;
        int garow = m0 + ra;
        if (garow < M) {
            const float* ap = A + (size_t)garow * K + k0 + ha;
            a0 = *(const float4*)(ap);
            a1 = *(const float4*)(ap + 4);
        }
        const float* wp = W + (size_t)(k0 + rw) * 128 + cw;
        float4 w0 = *(const float4*)(wp);
        float4 w1 = *(const float4*)(wp + 4);
        __syncthreads();
        As[ha + 0][ra] = a0.x; As[ha + 1][ra] = a0.y; As[ha + 2][ra] = a0.z; As[ha + 3][ra] = a0.w;
        As[ha + 4][ra] = a1.x; As[ha + 5][ra] = a1.y; As[ha + 6][ra] = a1.z; As[ha + 7][ra] = a1.w;
        *(float4*)&Ws[rw][cw]     = w0;
        *(float4*)&Ws[rw][cw + 4] = w1;
        __syncthreads();
#pragma unroll
        for (int kk = 0; kk < 16; ++kk) {
            float ar[8], wr[8];
            *(float4*)&ar[0] = *(const float4*)&As[kk][tm * 8];
            *(float4*)&ar[4] = *(const float4*)&As[kk][tm * 8 + 4];
            *(float4*)&wr[0] = *(const float4*)&Ws[kk][tn * 8];
            *(float4*)&wr[4] = *(const float4*)&Ws[kk][tn * 8 + 4];
#pragma unroll
            for (int i = 0; i < 8; ++i)
#pragma unroll
                for (int j = 0; j < 8; ++j)
                    acc[i][j] = fmaf(ar[i], wr[j], acc[i][j]);
        }
    }
#pragma unroll
    for (int i = 0; i < 8; ++i) {
        int r = m0 + tm * 8 + i;
        if (r < M) {
            float* op = out + (size_t)r * 128 + tn * 8;
#pragma unroll
            for (int j = 0; j < 8; ++j) {
                float v = acc[i][j] + bias[tn * 8 + j];
                if (ELU_OUT) v = eluf(v);
                op[j] = v;
            }
        }
    }
}

// ---------------- hop-0 attention: z = h * g ----------------
__global__ void hop0_kernel(const float* __restrict__ h, const float* __restrict__ att0,
                            const float* __restrict__ hb, float* __restrict__ z, int n) {
    int id = blockIdx.x * blockDim.x + threadIdx.x;
    if (id >= n * NH) return;
    int node = id >> 3, hd = id & 7;
    const float* hp = h + (size_t)node * HC + hd * NC;
    float v[16];
    *(float4*)&v[0]  = *(const float4*)(hp);
    *(float4*)&v[4]  = *(const float4*)(hp + 4);
    *(float4*)&v[8]  = *(const float4*)(hp + 8);
    *(float4*)&v[12] = *(const float4*)(hp + 12);
    float g = hb[hd];
#pragma unroll
    for (int c = 0; c < 16; ++c) g += att0[hd * 16 + c] * eluf(v[c]);
    float* zp = z + (size_t)node * HC + hd * NC;
    float o[16];
#pragma unroll
    for (int c = 0; c < 16; ++c) o[c] = v[c] * g;
    *(float4*)(zp)      = *(float4*)&o[0];
    *(float4*)(zp + 4)  = *(float4*)&o[4];
    *(float4*)(zp + 8)  = *(float4*)&o[8];
    *(float4*)(zp + 12) = *(float4*)&o[12];
}

// ---------------- pass A: edge attention + degree (one wave per node) ----------------
__global__ __launch_bounds__(256)
void passA_kernel(const float* __restrict__ z, const int* __restrict__ ptr,
                  const int* __restrict__ src, const float* __restrict__ att,
                  float decay, float* __restrict__ a_e, float* __restrict__ deg, int n) {
    int wave = (int)((blockIdx.x * (unsigned)blockDim.x + threadIdx.x) >> 6);
    if (wave >= n) return;
    int lane = threadIdx.x & 63;
    int hd = lane >> 3, c2 = lane & 7;
    int i = wave;
    const float* zi_p = z + (size_t)i * HC + hd * NC + c2 * 2;
    float2 zi = *(const float2*)zi_p;
    zi.x *= decay; zi.y *= decay;
    float2 av = *(const float2*)(att + hd * NC + c2 * 2);
    int s0 = ptr[i], s1 = ptr[i + 1];
    float dacc = 0.f;
    int s = s0;
    for (; s + 1 < s1; s += 2) {
        int j0 = src[s];
        int j1 = src[s + 1];
        float2 zj0 = *(const float2*)(z + (size_t)j0 * HC + hd * NC + c2 * 2);
        float2 zj1 = *(const float2*)(z + (size_t)j1 * HC + hd * NC + c2 * 2);
        float p0 = av.x * eluf(zi.x + zj0.x * decay) + av.y * eluf(zi.y + zj0.y * decay);
        float p1 = av.x * eluf(zi.x + zj1.x * decay) + av.y * eluf(zi.y + zj1.y * decay);
        p0 += __shfl_xor(p0, 1); p1 += __shfl_xor(p1, 1);
        p0 += __shfl_xor(p0, 2); p1 += __shfl_xor(p1, 2);
        p0 += __shfl_xor(p0, 4); p1 += __shfl_xor(p1, 4);
        if (c2 == 0) {
            float a0 = splusf(p0) + 1e-6f;
            float a1 = splusf(p1) + 1e-6f;
            a_e[(size_t)s * NH + hd] = a0;
            a_e[(size_t)(s + 1) * NH + hd] = a1;
            dacc += a0 + a1;
        }
    }
    if (s < s1) {
        int j = src[s];
        float2 zj = *(const float2*)(z + (size_t)j * HC + hd * NC + c2 * 2);
        float p = av.x * eluf(zi.x + zj.x * decay) + av.y * eluf(zi.y + zj.y * decay);
        p += __shfl_xor(p, 1);
        p += __shfl_xor(p, 2);
        p += __shfl_xor(p, 4);
        if (c2 == 0) {
            float aval = splusf(p) + 1e-6f;
            a_e[(size_t)s * NH + hd] = aval;
            dacc += aval;
        }
    }
    if (c2 == 0) deg[(size_t)i * NH + hd] = dacc;
}

__global__ void dinv_kernel(float* __restrict__ deg, int total) {
    int id = blockIdx.x * blockDim.x + threadIdx.x;
    if (id >= total) return;
    float d = deg[id];
    deg[id] = (d > 0.f) ? (1.f / sqrtf(d)) : 0.f;
}

// ---------------- pass B: propagate + hop attention + z update (one block per node) ----
__global__ __launch_bounds__(128)
void passB_kernel(const float* __restrict__ h_in, float* __restrict__ z,
                  const int* __restrict__ ptr, const int* __restrict__ src,
                  const float* __restrict__ a_e, const float* __restrict__ dinv,
                  const float* __restrict__ hatt, const float* __restrict__ hb,
                  float decay, float* __restrict__ h_out, int n) {
    int i = blockIdx.x;
    if (i >= n) return;
    int tid = threadIdx.x;
    int hd = tid >> 4, c = tid & 15;
    float di = dinv[(size_t)i * NH + hd];
    int s0 = ptr[i], s1 = ptr[i + 1];
    float acc = 0.f;
    int s = s0;
    for (; s + 1 < s1; s += 2) {
        int j0 = src[s];
        int j1 = src[s + 1];
        float w0 = a_e[(size_t)s * NH + hd] * dinv[(size_t)j0 * NH + hd];
        float w1 = a_e[(size_t)(s + 1) * NH + hd] * dinv[(size_t)j1 * NH + hd];
        float f0 = h_in[(size_t)j0 * HC + tid];
        float f1 = h_in[(size_t)j1 * HC + tid];
        acc = fmaf(w0, f0, acc);
        acc = fmaf(w1, f1, acc);
    }
    if (s < s1) {
        int j = src[s];
        float w = a_e[(size_t)s * NH + hd] * dinv[(size_t)j * NH + hd];
        acc = fmaf(w, h_in[(size_t)j * HC + tid], acc);
    }
    float hn = di * acc;
    h_out[(size_t)i * HC + tid] = hn;
    float zv = z[(size_t)i * HC + tid];
    float zs = zv * decay;
    float p = hatt[hd * 32 + c] * eluf(hn) + hatt[hd * 32 + 16 + c] * eluf(zs);
    p += __shfl_xor(p, 1);
    p += __shfl_xor(p, 2);
    p += __shfl_xor(p, 4);
    p += __shfl_xor(p, 8);
    float g = p + hb[hd];
    z[(size_t)i * HC + tid] = zv + hn * g;
}

// ---------------- output GEMM: out[M x 40] = elu(z)[M x 128] @ Wout + bout --------------
__global__ __launch_bounds__(256)
void gout_kernel(const float* __restrict__ z, const float* __restrict__ W,
                 const float* __restrict__ bias, float* __restrict__ out, int M) {
    __shared__ float zs[128 * 65];   // [k][r], stride 65
    __shared__ float ws[128 * 40];   // [k][n]
    const int tid = threadIdx.x;
    const int r0 = blockIdx.x * 64;
    for (int idx = tid; idx < 128 * 40; idx += 256) ws[idx] = W[idx];
    const int r = tid >> 2;   // 0..63
    const int q = tid & 3;    // 0..3
    {
        int grow = r0 + r;
#pragma unroll
        for (int t = 0; t < 8; ++t) {
            int k = q * 4 + t * 16;
            float4 v = make_float4(0.f, 0.f, 0.f, 0.f);
            if (grow < M) v = *(const float4*)(z + (size_t)grow * HC + k);
            zs[(k + 0) * 65 + r] = eluf(v.x);
            zs[(k + 1) * 65 + r] = eluf(v.y);
            zs[(k + 2) * 65 + r] = eluf(v.z);
            zs[(k + 3) * 65 + r] = eluf(v.w);
        }
    }
    __syncthreads();
    float acc[10];
#pragma unroll
    for (int j = 0; j < 10; ++j) acc[j] = bias[q * 10 + j];
    for (int k = 0; k < 128; ++k) {
        float zk = zs[k * 65 + r];
#pragma unroll
        for (int j = 0; j < 10; ++j)
            acc[j] = fmaf(zk, ws[k * 40 + q * 10 + j], acc[j]);
    }
    int grow = r0 + r;
    if (grow < M) {
        float* op = out + (size_t)grow * 40 + q * 10;
#pragma unroll
        for (int j = 0; j < 10; ++j) op[j] = acc[j];
    }
}

extern "C" void kernel_launch(void* const* d_in, const int* in_sizes, int n_in,
                              void* d_out, int out_size, void* d_ws, size_t ws_size,
                              hipStream_t stream) {
    (void)n_in; (void)out_size; (void)ws_size;
    const float* x    = (const float*)d_in[0];
    const int*   ei   = (const int*)d_in[1];
    const float* W0   = (const float*)d_in[2];
    const float* b0   = (const float*)d_in[3];
    const float* W1   = (const float*)d_in[4];
    const float* b1   = (const float*)d_in[5];
    const float* Wout = (const float*)d_in[6];
    const float* bout = (const float*)d_in[7];
    const float* att0 = (const float*)d_in[8];
    const float* hatts= (const float*)d_in[9];
    const float* atts = (const float*)d_in[10];
    const float* hb   = (const float*)d_in[11];
    float* out = (float*)d_out;

    const int N  = in_sizes[0] / 256;
    const int E  = in_sizes[1] / 2;
    const int E2 = E + N;

    char* p = (char*)d_ws;
    auto carve = [&](size_t bytes) -> char* {
        char* r = p;
        p += (bytes + 255) & ~(size_t)255;
        return r;
    };
    float* h1      = (float*)carve((size_t)N * HC * 4);
    float* hbuf    = (float*)carve((size_t)N * HC * 4);
    float* zbuf    = (float*)carve((size_t)N * HC * 4);
    float* a_e     = (float*)carve((size_t)E2 * NH * 4);
    float* degb    = (float*)carve((size_t)N * NH * 4);
    int* csr_ptr   = (int*)carve((size_t)(N + 1) * 4);
    int* csr_src   = (int*)carve((size_t)E2 * 4);
    int* cursor    = (int*)carve((size_t)N * 4);
    int* partials  = (int*)carve(1024 * 4);

    float decay[5];
    for (int k = 0; k <= 4; ++k) decay[k] = (float)log(1.0 / (k + 1) + 1.0 + 1e-6);

    // ---- CSR build (by destination col) ----
    hipMemsetAsync(cursor, 0, (size_t)N * 4, stream);
    int eb = (E2 + 255) / 256;
    int nb = (N + 255) / 256;
    count_kernel<<<eb, 256, 0, stream>>>(ei, cursor, E, E2);
    scan1_kernel<<<nb, 256, 0, stream>>>(cursor, csr_ptr, partials, N);
    scan2_kernel<<<1, 256, 0, stream>>>(partials, nb);
    scan3_kernel<<<nb, 256, 0, stream>>>(csr_ptr, partials, N, E2);
    hipMemsetAsync(cursor, 0, (size_t)N * 4, stream);
    fill_kernel<<<eb, 256, 0, stream>>>(ei, csr_ptr, cursor, csr_src, E, E2);

    // ---- MLP ----
    int gb = (N + 127) / 128;
    mlp_gemm<256, true ><<<gb, 256, 0, stream>>>(x,  W0, b0, h1,   N);
    mlp_gemm<128, false><<<gb, 256, 0, stream>>>(h1, W1, b1, hbuf, N);

    // ---- hop 0 ----
    hop0_kernel<<<(N * NH + 255) / 256, 256, 0, stream>>>(hbuf, att0, hb, zbuf, N);

    // ---- hops 1..4 ----
    float* hin  = hbuf;
    float* hout = h1;
    for (int k = 1; k <= 4; ++k) {
        passA_kernel<<<(N + 3) / 4, 256, 0, stream>>>(zbuf, csr_ptr, csr_src,
                                                      atts + (size_t)(k - 1) * NH * NC,
                                                      decay[k - 1], a_e, degb, N);
        dinv_kernel<<<(N * NH + 255) / 256, 256, 0, stream>>>(degb, N * NH);
        passB_kernel<<<N, 128, 0, stream>>>(hin, zbuf, csr_ptr, csr_src, a_e, degb,
                                            hatts + (size_t)(k - 1) * NH * 32,
                                            hb + (size_t)k * NH, decay[k - 1], hout, N);
        float* t = hin; hin = hout; hout = t;
    }

    // ---- classifier ----
    gout_kernel<<<(N + 63) / 64, 256, 0, stream>>>(zbuf, Wout, bout, out, N);
}

// Round 3
// 935.584 us; speedup vs baseline: 1.7234x; 1.0420x over previous
//
#include <hip/hip_runtime.h>
#include <math.h>

#define NH 8
#define NC 16
#define HC 128

// Fast transcendentals: v_exp_f32 / v_log_f32 hardware paths (~1 ulp).
__device__ __forceinline__ float eluf(float x) { return x > 0.f ? x : __expf(x) - 1.f; }
__device__ __forceinline__ float splusf(float x) { return fmaxf(x, 0.f) + __logf(1.f + __expf(-fabsf(x))); }

// ---------------- CSR build ----------------
__global__ void count_kernel(const int* __restrict__ ei, int* __restrict__ cnt, int E, int E2) {
    int e = blockIdx.x * blockDim.x + threadIdx.x;
    if (e >= E2) return;
    int col = (e < E) ? ei[E + e] : (e - E);
    atomicAdd(&cnt[col], 1);
}

__global__ void scan1_kernel(const int* __restrict__ counts, int* __restrict__ ptr,
                             int* __restrict__ partials, int n) {
    __shared__ int tmp[256];
    int t = threadIdx.x;
    int i = blockIdx.x * 256 + t;
    int v = (i < n) ? counts[i] : 0;
    tmp[t] = v;
    __syncthreads();
    for (int off = 1; off < 256; off <<= 1) {
        int add = (t >= off) ? tmp[t - off] : 0;
        __syncthreads();
        tmp[t] += add;
        __syncthreads();
    }
    if (i < n) ptr[i] = tmp[t] - v;            // block-local exclusive
    if (t == 255) partials[blockIdx.x] = tmp[255];
}

__global__ void scan2_kernel(int* __restrict__ partials, int nb) {
    __shared__ int tmp[256];
    int t = threadIdx.x;
    int v = (t < nb) ? partials[t] : 0;
    tmp[t] = v;
    __syncthreads();
    for (int off = 1; off < 256; off <<= 1) {
        int add = (t >= off) ? tmp[t - off] : 0;
        __syncthreads();
        tmp[t] += add;
        __syncthreads();
    }
    if (t < nb) partials[t] = tmp[t] - v;      // exclusive
}

__global__ void scan3_kernel(int* __restrict__ ptr, const int* __restrict__ partials,
                             int n, int total) {
    int i = blockIdx.x * 256 + threadIdx.x;
    if (i < n) ptr[i] += partials[blockIdx.x];
    if (i == 0) ptr[n] = total;
}

__global__ void fill_kernel(const int* __restrict__ ei, const int* __restrict__ ptr,
                            int* __restrict__ cursor, int* __restrict__ src, int E, int E2) {
    int e = blockIdx.x * blockDim.x + threadIdx.x;
    if (e >= E2) return;
    int col, row;
    if (e < E) { row = ei[e]; col = ei[E + e]; }
    else       { row = e - E; col = e - E; }
    int pos = ptr[col] + atomicAdd(&cursor[col], 1);
    src[pos] = row;
}

// ---------------- fp32 GEMM: out[M x 128] = act(A[M x K] @ W[K x 128] + b) ----------------
template<int K, bool ELU_OUT>
__global__ __launch_bounds__(256)
void mlp_gemm(const float* __restrict__ A, const float* __restrict__ W,
              const float* __restrict__ bias, float* __restrict__ out, int M) {
    __shared__ float As[16][132];   // [k][m], padded
    __shared__ float Ws[16][128];   // [k][n]
    const int tid = threadIdx.x;
    const int m0 = blockIdx.x * 128;
    const int tm = tid >> 4;        // 0..15
    const int tn = tid & 15;        // 0..15
    float acc[8][8];
#pragma unroll
    for (int i = 0; i < 8; ++i)
#pragma unroll
        for (int j = 0; j < 8; ++j) acc[i][j] = 0.f;

    const int ra = tid >> 1;            // 0..127 (A tile row)
    const int ha = (tid & 1) * 8;       // k-offset half
    const int rw = tid >> 4;            // 0..15 (W tile row)
    const int cw = (tid & 15) * 8;      // W col

    for (int k0 = 0; k0 < K; k0 += 16) {
        float4 a0 = make_float4(0.f, 0.f, 0.f, 0.f), a1 = a0;
        int garow = m0 + ra;
        if (garow < M) {
            const float* ap = A + (size_t)garow * K + k0 + ha;
            a0 = *(const float4*)(ap);
            a1 = *(const float4*)(ap + 4);
        }
        const float* wp = W + (size_t)(k0 + rw) * 128 + cw;
        float4 w0 = *(const float4*)(wp);
        float4 w1 = *(const float4*)(wp + 4);
        __syncthreads();
        As[ha + 0][ra] = a0.x; As[ha + 1][ra] = a0.y; As[ha + 2][ra] = a0.z; As[ha + 3][ra] = a0.w;
        As[ha + 4][ra] = a1.x; As[ha + 5][ra] = a1.y; As[ha + 6][ra] = a1.z; As[ha + 7][ra] = a1.w;
        *(float4*)&Ws[rw][cw]     = w0;
        *(float4*)&Ws[rw][cw + 4] = w1;
        __syncthreads();
#pragma unroll
        for (int kk = 0; kk < 16; ++kk) {
            float ar[8], wr[8];
            *(float4*)&ar[0] = *(const float4*)&As[kk][tm * 8];
            *(float4*)&ar[4] = *(const float4*)&As[kk][tm * 8 + 4];
            *(float4*)&wr[0] = *(const float4*)&Ws[kk][tn * 8];
            *(float4*)&wr[4] = *(const float4*)&Ws[kk][tn * 8 + 4];
#pragma unroll
            for (int i = 0; i < 8; ++i)
#pragma unroll
                for (int j = 0; j < 8; ++j)
                    acc[i][j] = fmaf(ar[i], wr[j], acc[i][j]);
        }
    }
#pragma unroll
    for (int i = 0; i < 8; ++i) {
        int r = m0 + tm * 8 + i;
        if (r < M) {
            float* op = out + (size_t)r * 128 + tn * 8;
#pragma unroll
            for (int j = 0; j < 8; ++j) {
                float v = acc[i][j] + bias[tn * 8 + j];
                if (ELU_OUT) v = eluf(v);
                op[j] = v;
            }
        }
    }
}

// ---------------- hop-0 attention: z = h * g ----------------
__global__ void hop0_kernel(const float* __restrict__ h, const float* __restrict__ att0,
                            const float* __restrict__ hb, float* __restrict__ z, int n) {
    int id = blockIdx.x * blockDim.x + threadIdx.x;
    if (id >= n * NH) return;
    int node = id >> 3, hd = id & 7;
    const float* hp = h + (size_t)node * HC + hd * NC;
    float v[16];
    *(float4*)&v[0]  = *(const float4*)(hp);
    *(float4*)&v[4]  = *(const float4*)(hp + 4);
    *(float4*)&v[8]  = *(const float4*)(hp + 8);
    *(float4*)&v[12] = *(const float4*)(hp + 12);
    float g = hb[hd];
#pragma unroll
    for (int c = 0; c < 16; ++c) g += att0[hd * 16 + c] * eluf(v[c]);
    float* zp = z + (size_t)node * HC + hd * NC;
    float o[16];
#pragma unroll
    for (int c = 0; c < 16; ++c) o[c] = v[c] * g;
    *(float4*)(zp)      = *(float4*)&o[0];
    *(float4*)(zp + 4)  = *(float4*)&o[4];
    *(float4*)(zp + 8)  = *(float4*)&o[8];
    *(float4*)(zp + 12) = *(float4*)&o[12];
}

// ---------------- pass A: edge attention + degree ----------------
// One wave per node; 2 edges in flight (one per 32-lane half).
// Lane = (half, q): q covers channels 4q..4q+3 via float4; head = q>>2.
// att flat is [8][16] = 128 floats, so channel c maps att_flat[c] directly.
__global__ __launch_bounds__(256)
void passA_kernel(const float* __restrict__ z, const int* __restrict__ ptr,
                  const int* __restrict__ src, const float* __restrict__ att,
                  float decay, float* __restrict__ a_e, float* __restrict__ deg, int n) {
    int wid = (int)((blockIdx.x * (unsigned)blockDim.x + threadIdx.x) >> 6);
    if (wid >= n) return;
    const int lane = threadIdx.x & 63;
    const int half = lane >> 5;       // which of 2 concurrent edges
    const int q    = lane & 31;       // channel quad
    const int hd   = q >> 2;          // head
    const unsigned i = (unsigned)wid;

    float4 zi = *(const float4*)(z + (i << 7) + (q << 2));
    zi.x *= decay; zi.y *= decay; zi.z *= decay; zi.w *= decay;
    const float4 av = *(const float4*)(att + (q << 2));

    int s0 = ptr[wid], s1 = ptr[wid + 1];
    float dacc = 0.f;
    for (int s = s0 + half; s < s1; s += 2) {
        unsigned j = (unsigned)src[s];
        const float4 zj = *(const float4*)(z + (j << 7) + (q << 2));
        float p;
        p  = av.x * eluf(fmaf(zj.x, decay, zi.x));
        p += av.y * eluf(fmaf(zj.y, decay, zi.y));
        p += av.z * eluf(fmaf(zj.z, decay, zi.z));
        p += av.w * eluf(fmaf(zj.w, decay, zi.w));
        p += __shfl_xor(p, 1);
        p += __shfl_xor(p, 2);
        if ((q & 3) == 0) {
            float aval = splusf(p) + 1e-6f;
            a_e[((unsigned)s << 3) + hd] = aval;
            dacc += aval;
        }
    }
    dacc += __shfl_xor(dacc, 32);
    if (half == 0 && (q & 3) == 0)
        deg[(i << 3) + hd] = dacc;
}

__global__ void dinv_kernel(float* __restrict__ deg, int total) {
    int id = blockIdx.x * blockDim.x + threadIdx.x;
    if (id >= total) return;
    float d = deg[id];
    deg[id] = (d > 0.f) ? (1.f / sqrtf(d)) : 0.f;
}

// ---------------- pass B: propagate + hop attention + z update ----------------
// One wave per node; lane covers channels 2*lane, 2*lane+1; head = lane>>3.
__global__ __launch_bounds__(256)
void passB_kernel(const float* __restrict__ h_in, float* __restrict__ z,
                  const int* __restrict__ ptr, const int* __restrict__ src,
                  const float* __restrict__ a_e, const float* __restrict__ dinv,
                  const float* __restrict__ hatt, const float* __restrict__ hb,
                  float decay, float* __restrict__ h_out, int n) {
    int wid = (int)((blockIdx.x * (unsigned)blockDim.x + threadIdx.x) >> 6);
    if (wid >= n) return;
    const int lane = threadIdx.x & 63;
    const int hd = lane >> 3;
    const unsigned coff = (unsigned)lane * 2u;
    const unsigned i = (unsigned)wid;
    float di = dinv[(i << 3) + hd];
    int s0 = ptr[wid], s1 = ptr[wid + 1];
    float ax = 0.f, ay = 0.f;
    int s = s0;
    for (; s + 1 < s1; s += 2) {
        unsigned j0 = (unsigned)src[s];
        unsigned j1 = (unsigned)src[s + 1];
        float w0 = a_e[((unsigned)s << 3) + hd]       * dinv[(j0 << 3) + hd];
        float w1 = a_e[((unsigned)(s + 1) << 3) + hd] * dinv[(j1 << 3) + hd];
        float2 f0 = *(const float2*)(h_in + (j0 << 7) + coff);
        float2 f1 = *(const float2*)(h_in + (j1 << 7) + coff);
        ax = fmaf(w0, f0.x, ax); ay = fmaf(w0, f0.y, ay);
        ax = fmaf(w1, f1.x, ax); ay = fmaf(w1, f1.y, ay);
    }
    if (s < s1) {
        unsigned j = (unsigned)src[s];
        float w = a_e[((unsigned)s << 3) + hd] * dinv[(j << 3) + hd];
        float2 f = *(const float2*)(h_in + (j << 7) + coff);
        ax = fmaf(w, f.x, ax); ay = fmaf(w, f.y, ay);
    }
    float hnx = di * ax, hny = di * ay;
    *(float2*)(h_out + (i << 7) + coff) = make_float2(hnx, hny);
    float2 zv = *(const float2*)(z + (i << 7) + coff);
    float zsx = zv.x * decay, zsy = zv.y * decay;
    const int c = (lane & 7) * 2;
    const float* hA = hatt + hd * 32;
    float p = hA[c]      * eluf(hnx) + hA[c + 1]      * eluf(hny)
            + hA[16 + c] * eluf(zsx) + hA[16 + c + 1] * eluf(zsy);
    p += __shfl_xor(p, 1);
    p += __shfl_xor(p, 2);
    p += __shfl_xor(p, 4);
    float g = p + hb[hd];
    *(float2*)(z + (i << 7) + coff) = make_float2(zv.x + hnx * g, zv.y + hny * g);
}

// ---------------- output GEMM: out[M x 40] = elu(z)[M x 128] @ Wout + bout --------------
__global__ __launch_bounds__(256)
void gout_kernel(const float* __restrict__ z, const float* __restrict__ W,
                 const float* __restrict__ bias, float* __restrict__ out, int M) {
    __shared__ float zs[128 * 65];   // [k][r], stride 65
    __shared__ float ws[128 * 40];   // [k][n]
    const int tid = threadIdx.x;
    const int r0 = blockIdx.x * 64;
    for (int idx = tid; idx < 128 * 40; idx += 256) ws[idx] = W[idx];
    const int r = tid >> 2;   // 0..63
    const int q = tid & 3;    // 0..3
    {
        int grow = r0 + r;
#pragma unroll
        for (int t = 0; t < 8; ++t) {
            int k = q * 4 + t * 16;
            float4 v = make_float4(0.f, 0.f, 0.f, 0.f);
            if (grow < M) v = *(const float4*)(z + (size_t)grow * HC + k);
            zs[(k + 0) * 65 + r] = eluf(v.x);
            zs[(k + 1) * 65 + r] = eluf(v.y);
            zs[(k + 2) * 65 + r] = eluf(v.z);
            zs[(k + 3) * 65 + r] = eluf(v.w);
        }
    }
    __syncthreads();
    float acc[10];
#pragma unroll
    for (int j = 0; j < 10; ++j) acc[j] = bias[q * 10 + j];
    for (int k = 0; k < 128; ++k) {
        float zk = zs[k * 65 + r];
#pragma unroll
        for (int j = 0; j < 10; ++j)
            acc[j] = fmaf(zk, ws[k * 40 + q * 10 + j], acc[j]);
    }
    int grow = r0 + r;
    if (grow < M) {
        float* op = out + (size_t)grow * 40 + q * 10;
#pragma unroll
        for (int j = 0; j < 10; ++j) op[j] = acc[j];
    }
}

extern "C" void kernel_launch(void* const* d_in, const int* in_sizes, int n_in,
                              void* d_out, int out_size, void* d_ws, size_t ws_size,
                              hipStream_t stream) {
    (void)n_in; (void)out_size; (void)ws_size;
    const float* x    = (const float*)d_in[0];
    const int*   ei   = (const int*)d_in[1];
    const float* W0   = (const float*)d_in[2];
    const float* b0   = (const float*)d_in[3];
    const float* W1   = (const float*)d_in[4];
    const float* b1   = (const float*)d_in[5];
    const float* Wout = (const float*)d_in[6];
    const float* bout = (const float*)d_in[7];
    const float* att0 = (const float*)d_in[8];
    const float* hatts= (const float*)d_in[9];
    const float* atts = (const float*)d_in[10];
    const float* hb   = (const float*)d_in[11];
    float* out = (float*)d_out;

    const int N  = in_sizes[0] / 256;
    const int E  = in_sizes[1] / 2;
    const int E2 = E + N;

    char* p = (char*)d_ws;
    auto carve = [&](size_t bytes) -> char* {
        char* r = p;
        p += (bytes + 255) & ~(size_t)255;
        return r;
    };
    float* h1      = (float*)carve((size_t)N * HC * 4);
    float* hbuf    = (float*)carve((size_t)N * HC * 4);
    float* zbuf    = (float*)carve((size_t)N * HC * 4);
    float* a_e     = (float*)carve((size_t)E2 * NH * 4);
    float* degb    = (float*)carve((size_t)N * NH * 4);
    int* csr_ptr   = (int*)carve((size_t)(N + 1) * 4);
    int* csr_src   = (int*)carve((size_t)E2 * 4);
    int* cursor    = (int*)carve((size_t)N * 4);
    int* partials  = (int*)carve(1024 * 4);

    float decay[5];
    for (int k = 0; k <= 4; ++k) decay[k] = (float)log(1.0 / (k + 1) + 1.0 + 1e-6);

    // ---- CSR build (by destination col) ----
    hipMemsetAsync(cursor, 0, (size_t)N * 4, stream);
    int eb = (E2 + 255) / 256;
    int nb = (N + 255) / 256;
    count_kernel<<<eb, 256, 0, stream>>>(ei, cursor, E, E2);
    scan1_kernel<<<nb, 256, 0, stream>>>(cursor, csr_ptr, partials, N);
    scan2_kernel<<<1, 256, 0, stream>>>(partials, nb);
    scan3_kernel<<<nb, 256, 0, stream>>>(csr_ptr, partials, N, E2);
    hipMemsetAsync(cursor, 0, (size_t)N * 4, stream);
    fill_kernel<<<eb, 256, 0, stream>>>(ei, csr_ptr, cursor, csr_src, E, E2);

    // ---- MLP ----
    int gb = (N + 127) / 128;
    mlp_gemm<256, true ><<<gb, 256, 0, stream>>>(x,  W0, b0, h1,   N);
    mlp_gemm<128, false><<<gb, 256, 0, stream>>>(h1, W1, b1, hbuf, N);

    // ---- hop 0 ----
    hop0_kernel<<<(N * NH + 255) / 256, 256, 0, stream>>>(hbuf, att0, hb, zbuf, N);

    // ---- hops 1..4 ----
    float* hin  = hbuf;
    float* hout = h1;
    int wb = (N + 3) / 4;   // 4 waves (nodes) per 256-thread block
    for (int k = 1; k <= 4; ++k) {
        passA_kernel<<<wb, 256, 0, stream>>>(zbuf, csr_ptr, csr_src,
                                             atts + (size_t)(k - 1) * NH * NC,
                                             decay[k - 1], a_e, degb, N);
        dinv_kernel<<<(N * NH + 255) / 256, 256, 0, stream>>>(degb, N * NH);
        passB_kernel<<<wb, 256, 0, stream>>>(hin, zbuf, csr_ptr, csr_src, a_e, degb,
                                             hatts + (size_t)(k - 1) * NH * 32,
                                             hb + (size_t)k * NH, decay[k - 1], hout, N);
        float* t = hin; hin = hout; hout = t;
    }

    // ---- classifier ----
    gout_kernel<<<(N + 63) / 64, 256, 0, stream>>>(zbuf, Wout, bout, out, N);
}

// Round 4
// 875.398 us; speedup vs baseline: 1.8419x; 1.0688x over previous
//
#include <hip/hip_runtime.h>
#include <math.h>

#define NH 8
#define NC 16
#define HC 128

// Fast transcendentals: v_exp_f32 / v_log_f32 hardware paths (~1 ulp).
__device__ __forceinline__ float eluf(float x) { return x > 0.f ? x : __expf(x) - 1.f; }
__device__ __forceinline__ float splusf(float x) { return fmaxf(x, 0.f) + __logf(1.f + __expf(-fabsf(x))); }

// ---------------- CSR build ----------------
__global__ void count_kernel(const int* __restrict__ ei, int* __restrict__ cnt, int E, int E2) {
    int e = blockIdx.x * blockDim.x + threadIdx.x;
    if (e >= E2) return;
    int col = (e < E) ? ei[E + e] : (e - E);
    atomicAdd(&cnt[col], 1);
}

__global__ void scan1_kernel(const int* __restrict__ counts, int* __restrict__ ptr,
                             int* __restrict__ partials, int n) {
    __shared__ int tmp[256];
    int t = threadIdx.x;
    int i = blockIdx.x * 256 + t;
    int v = (i < n) ? counts[i] : 0;
    tmp[t] = v;
    __syncthreads();
    for (int off = 1; off < 256; off <<= 1) {
        int add = (t >= off) ? tmp[t - off] : 0;
        __syncthreads();
        tmp[t] += add;
        __syncthreads();
    }
    if (i < n) ptr[i] = tmp[t] - v;            // block-local exclusive
    if (t == 255) partials[blockIdx.x] = tmp[255];
}

__global__ void scan2_kernel(int* __restrict__ partials, int nb) {
    __shared__ int tmp[256];
    int t = threadIdx.x;
    int v = (t < nb) ? partials[t] : 0;
    tmp[t] = v;
    __syncthreads();
    for (int off = 1; off < 256; off <<= 1) {
        int add = (t >= off) ? tmp[t - off] : 0;
        __syncthreads();
        tmp[t] += add;
        __syncthreads();
    }
    if (t < nb) partials[t] = tmp[t] - v;      // exclusive
}

__global__ void scan3_kernel(int* __restrict__ ptr, const int* __restrict__ partials,
                             int n, int total) {
    int i = blockIdx.x * 256 + threadIdx.x;
    if (i < n) ptr[i] += partials[blockIdx.x];
    if (i == 0) ptr[n] = total;
}

__global__ void fill_kernel(const int* __restrict__ ei, const int* __restrict__ ptr,
                            int* __restrict__ cursor, int* __restrict__ src, int E, int E2) {
    int e = blockIdx.x * blockDim.x + threadIdx.x;
    if (e >= E2) return;
    int col, row;
    if (e < E) { row = ei[e]; col = ei[E + e]; }
    else       { row = e - E; col = e - E; }
    int pos = ptr[col] + atomicAdd(&cursor[col], 1);
    src[pos] = row;
}

// ---------------- fp32 GEMM: out[M x 128] = act(A[M x K] @ W[K x 128] + b) ----------------
template<int K, bool ELU_OUT>
__global__ __launch_bounds__(256)
void mlp_gemm(const float* __restrict__ A, const float* __restrict__ W,
              const float* __restrict__ bias, float* __restrict__ out, int M) {
    __shared__ float As[16][132];   // [k][m], padded
    __shared__ float Ws[16][128];   // [k][n]
    const int tid = threadIdx.x;
    const int m0 = blockIdx.x * 128;
    const int tm = tid >> 4;        // 0..15
    const int tn = tid & 15;        // 0..15
    float acc[8][8];
#pragma unroll
    for (int i = 0; i < 8; ++i)
#pragma unroll
        for (int j = 0; j < 8; ++j) acc[i][j] = 0.f;

    const int ra = tid >> 1;            // 0..127 (A tile row)
    const int ha = (tid & 1) * 8;       // k-offset half
    const int rw = tid >> 4;            // 0..15 (W tile row)
    const int cw = (tid & 15) * 8;      // W col

    for (int k0 = 0; k0 < K; k0 += 16) {
        float4 a0 = make_float4(0.f, 0.f, 0.f, 0.f), a1 = a0;
        int garow = m0 + ra;
        if (garow < M) {
            const float* ap = A + (size_t)garow * K + k0 + ha;
            a0 = *(const float4*)(ap);
            a1 = *(const float4*)(ap + 4);
        }
        const float* wp = W + (size_t)(k0 + rw) * 128 + cw;
        float4 w0 = *(const float4*)(wp);
        float4 w1 = *(const float4*)(wp + 4);
        __syncthreads();
        As[ha + 0][ra] = a0.x; As[ha + 1][ra] = a0.y; As[ha + 2][ra] = a0.z; As[ha + 3][ra] = a0.w;
        As[ha + 4][ra] = a1.x; As[ha + 5][ra] = a1.y; As[ha + 6][ra] = a1.z; As[ha + 7][ra] = a1.w;
        *(float4*)&Ws[rw][cw]     = w0;
        *(float4*)&Ws[rw][cw + 4] = w1;
        __syncthreads();
#pragma unroll
        for (int kk = 0; kk < 16; ++kk) {
            float ar[8], wr[8];
            *(float4*)&ar[0] = *(const float4*)&As[kk][tm * 8];
            *(float4*)&ar[4] = *(const float4*)&As[kk][tm * 8 + 4];
            *(float4*)&wr[0] = *(const float4*)&Ws[kk][tn * 8];
            *(float4*)&wr[4] = *(const float4*)&Ws[kk][tn * 8 + 4];
#pragma unroll
            for (int i = 0; i < 8; ++i)
#pragma unroll
                for (int j = 0; j < 8; ++j)
                    acc[i][j] = fmaf(ar[i], wr[j], acc[i][j]);
        }
    }
#pragma unroll
    for (int i = 0; i < 8; ++i) {
        int r = m0 + tm * 8 + i;
        if (r < M) {
            float* op = out + (size_t)r * 128 + tn * 8;
#pragma unroll
            for (int j = 0; j < 8; ++j) {
                float v = acc[i][j] + bias[tn * 8 + j];
                if (ELU_OUT) v = eluf(v);
                op[j] = v;
            }
        }
    }
}

// ---------------- hop-0 attention: z = h * g ----------------
__global__ void hop0_kernel(const float* __restrict__ h, const float* __restrict__ att0,
                            const float* __restrict__ hb, float* __restrict__ z, int n) {
    int id = blockIdx.x * blockDim.x + threadIdx.x;
    if (id >= n * NH) return;
    int node = id >> 3, hd = id & 7;
    const float* hp = h + (size_t)node * HC + hd * NC;
    float v[16];
    *(float4*)&v[0]  = *(const float4*)(hp);
    *(float4*)&v[4]  = *(const float4*)(hp + 4);
    *(float4*)&v[8]  = *(const float4*)(hp + 8);
    *(float4*)&v[12] = *(const float4*)(hp + 12);
    float g = hb[hd];
#pragma unroll
    for (int c = 0; c < 16; ++c) g += att0[hd * 16 + c] * eluf(v[c]);
    float* zp = z + (size_t)node * HC + hd * NC;
    float o[16];
#pragma unroll
    for (int c = 0; c < 16; ++c) o[c] = v[c] * g;
    *(float4*)(zp)      = *(float4*)&o[0];
    *(float4*)(zp + 4)  = *(float4*)&o[4];
    *(float4*)(zp + 8)  = *(float4*)&o[8];
    *(float4*)(zp + 12) = *(float4*)&o[12];
}

// ---------------- pass A: edge attention + degree + dinv (fused) ----------------
// One wave per node; 2 edges in flight (one per 32-lane half) x unroll-2
// => 4 independent 512 B row gathers outstanding.
// Lane = (half, q): q covers channels 4q..4q+3 via float4; head = q>>2.
__global__ __launch_bounds__(256)
void passA_kernel(const float* __restrict__ z, const int* __restrict__ ptr,
                  const int* __restrict__ src, const float* __restrict__ att,
                  float decay, float* __restrict__ a_e, float* __restrict__ dinv, int n) {
    int wid = (int)((blockIdx.x * 256u + threadIdx.x) >> 6);
    if (wid >= n) return;
    const int lane = threadIdx.x & 63;
    const int half = lane >> 5;       // which of 2 concurrent edges
    const int q    = lane & 31;       // channel quad
    const int hd   = q >> 2;          // head
    const unsigned i = (unsigned)wid;

    float4 zi = *(const float4*)(z + (i << 7) + (q << 2));
    zi.x *= decay; zi.y *= decay; zi.z *= decay; zi.w *= decay;
    const float4 av = *(const float4*)(att + (q << 2));

    int s0 = ptr[wid], s1 = ptr[wid + 1];
    float dacc = 0.f;
    int s = s0 + half;
    for (; s + 2 < s1; s += 4) {
        unsigned j0 = (unsigned)src[s];
        unsigned j1 = (unsigned)src[s + 2];
        const float4 r0 = *(const float4*)(z + (j0 << 7) + (q << 2));
        const float4 r1 = *(const float4*)(z + (j1 << 7) + (q << 2));
        float p0, p1;
        p0  = av.x * eluf(fmaf(r0.x, decay, zi.x));
        p0 += av.y * eluf(fmaf(r0.y, decay, zi.y));
        p0 += av.z * eluf(fmaf(r0.z, decay, zi.z));
        p0 += av.w * eluf(fmaf(r0.w, decay, zi.w));
        p1  = av.x * eluf(fmaf(r1.x, decay, zi.x));
        p1 += av.y * eluf(fmaf(r1.y, decay, zi.y));
        p1 += av.z * eluf(fmaf(r1.z, decay, zi.z));
        p1 += av.w * eluf(fmaf(r1.w, decay, zi.w));
        p0 += __shfl_xor(p0, 1); p1 += __shfl_xor(p1, 1);
        p0 += __shfl_xor(p0, 2); p1 += __shfl_xor(p1, 2);
        if ((q & 3) == 0) {
            float a0 = splusf(p0) + 1e-6f;
            float a1 = splusf(p1) + 1e-6f;
            a_e[((unsigned)s << 3) + hd] = a0;
            a_e[((unsigned)(s + 2) << 3) + hd] = a1;
            dacc += a0 + a1;
        }
    }
    for (; s < s1; s += 2) {
        unsigned j = (unsigned)src[s];
        const float4 r = *(const float4*)(z + (j << 7) + (q << 2));
        float p;
        p  = av.x * eluf(fmaf(r.x, decay, zi.x));
        p += av.y * eluf(fmaf(r.y, decay, zi.y));
        p += av.z * eluf(fmaf(r.z, decay, zi.z));
        p += av.w * eluf(fmaf(r.w, decay, zi.w));
        p += __shfl_xor(p, 1);
        p += __shfl_xor(p, 2);
        if ((q & 3) == 0) {
            float aval = splusf(p) + 1e-6f;
            a_e[((unsigned)s << 3) + hd] = aval;
            dacc += aval;
        }
    }
    dacc += __shfl_xor(dacc, 32);
    if (half == 0 && (q & 3) == 0) {
        dinv[(i << 3) + hd] = (dacc > 0.f) ? (1.f / sqrtf(dacc)) : 0.f;
    }
}

// ---------------- pass B: propagate + hop attention + z update ----------------
// Same half-wave layout as passA: 2 edges in flight x unroll-2.
__global__ __launch_bounds__(256)
void passB_kernel(const float* __restrict__ h_in, float* __restrict__ z,
                  const int* __restrict__ ptr, const int* __restrict__ src,
                  const float* __restrict__ a_e, const float* __restrict__ dinv,
                  const float* __restrict__ hatt, const float* __restrict__ hb,
                  float decay, float* __restrict__ h_out, int n, int store_h) {
    int wid = (int)((blockIdx.x * 256u + threadIdx.x) >> 6);
    if (wid >= n) return;
    const int lane = threadIdx.x & 63;
    const int half = lane >> 5;
    const int q    = lane & 31;
    const int hd   = q >> 2;
    const unsigned i = (unsigned)wid;

    const float di = dinv[(i << 3) + hd];
    int s0 = ptr[wid], s1 = ptr[wid + 1];
    float ax = 0.f, ay = 0.f, az = 0.f, aw = 0.f;
    int s = s0 + half;
    for (; s + 2 < s1; s += 4) {
        unsigned j0 = (unsigned)src[s];
        unsigned j1 = (unsigned)src[s + 2];
        float w0 = a_e[((unsigned)s << 3) + hd]       * dinv[(j0 << 3) + hd];
        float w1 = a_e[((unsigned)(s + 2) << 3) + hd] * dinv[(j1 << 3) + hd];
        const float4 f0 = *(const float4*)(h_in + (j0 << 7) + (q << 2));
        const float4 f1 = *(const float4*)(h_in + (j1 << 7) + (q << 2));
        ax = fmaf(w0, f0.x, ax); ay = fmaf(w0, f0.y, ay);
        az = fmaf(w0, f0.z, az); aw = fmaf(w0, f0.w, aw);
        ax = fmaf(w1, f1.x, ax); ay = fmaf(w1, f1.y, ay);
        az = fmaf(w1, f1.z, az); aw = fmaf(w1, f1.w, aw);
    }
    for (; s < s1; s += 2) {
        unsigned j = (unsigned)src[s];
        float w = a_e[((unsigned)s << 3) + hd] * dinv[(j << 3) + hd];
        const float4 f = *(const float4*)(h_in + (j << 7) + (q << 2));
        ax = fmaf(w, f.x, ax); ay = fmaf(w, f.y, ay);
        az = fmaf(w, f.z, az); aw = fmaf(w, f.w, aw);
    }
    // combine the two halves (each accumulated a disjoint set of edges)
    ax += __shfl_xor(ax, 32);
    ay += __shfl_xor(ay, 32);
    az += __shfl_xor(az, 32);
    aw += __shfl_xor(aw, 32);

    const float4 hn = make_float4(di * ax, di * ay, di * az, di * aw);
    const float4 zv = *(const float4*)(z + (i << 7) + (q << 2));
    const float* hA = hatt + hd * 32 + ((q & 3) << 2);
    float p;
    p  = hA[0] * eluf(hn.x) + hA[1] * eluf(hn.y)
       + hA[2] * eluf(hn.z) + hA[3] * eluf(hn.w);
    p += hA[16] * eluf(zv.x * decay) + hA[17] * eluf(zv.y * decay)
       + hA[18] * eluf(zv.z * decay) + hA[19] * eluf(zv.w * decay);
    p += __shfl_xor(p, 1);
    p += __shfl_xor(p, 2);
    const float g = p + hb[hd];
    if (half == 0) {
        if (store_h)
            *(float4*)(h_out + (i << 7) + (q << 2)) = hn;
        *(float4*)(z + (i << 7) + (q << 2)) =
            make_float4(zv.x + hn.x * g, zv.y + hn.y * g,
                        zv.z + hn.z * g, zv.w + hn.w * g);
    }
}

// ---------------- output GEMM: out[M x 40] = elu(z)[M x 128] @ Wout + bout --------------
__global__ __launch_bounds__(256)
void gout_kernel(const float* __restrict__ z, const float* __restrict__ W,
                 const float* __restrict__ bias, float* __restrict__ out, int M) {
    __shared__ float zs[128 * 65];   // [k][r], stride 65
    __shared__ float ws[128 * 40];   // [k][n]
    const int tid = threadIdx.x;
    const int r0 = blockIdx.x * 64;
    for (int idx = tid; idx < 128 * 40; idx += 256) ws[idx] = W[idx];
    const int r = tid >> 2;   // 0..63
    const int q = tid & 3;    // 0..3
    {
        int grow = r0 + r;
#pragma unroll
        for (int t = 0; t < 8; ++t) {
            int k = q * 4 + t * 16;
            float4 v = make_float4(0.f, 0.f, 0.f, 0.f);
            if (grow < M) v = *(const float4*)(z + (size_t)grow * HC + k);
            zs[(k + 0) * 65 + r] = eluf(v.x);
            zs[(k + 1) * 65 + r] = eluf(v.y);
            zs[(k + 2) * 65 + r] = eluf(v.z);
            zs[(k + 3) * 65 + r] = eluf(v.w);
        }
    }
    __syncthreads();
    float acc[10];
#pragma unroll
    for (int j = 0; j < 10; ++j) acc[j] = bias[q * 10 + j];
    for (int k = 0; k < 128; ++k) {
        float zk = zs[k * 65 + r];
#pragma unroll
        for (int j = 0; j < 10; ++j)
            acc[j] = fmaf(zk, ws[k * 40 + q * 10 + j], acc[j]);
    }
    int grow = r0 + r;
    if (grow < M) {
        float* op = out + (size_t)grow * 40 + q * 10;
#pragma unroll
        for (int j = 0; j < 10; ++j) op[j] = acc[j];
    }
}

extern "C" void kernel_launch(void* const* d_in, const int* in_sizes, int n_in,
                              void* d_out, int out_size, void* d_ws, size_t ws_size,
                              hipStream_t stream) {
    (void)n_in; (void)out_size; (void)ws_size;
    const float* x    = (const float*)d_in[0];
    const int*   ei   = (const int*)d_in[1];
    const float* W0   = (const float*)d_in[2];
    const float* b0   = (const float*)d_in[3];
    const float* W1   = (const float*)d_in[4];
    const float* b1   = (const float*)d_in[5];
    const float* Wout = (const float*)d_in[6];
    const float* bout = (const float*)d_in[7];
    const float* att0 = (const float*)d_in[8];
    const float* hatts= (const float*)d_in[9];
    const float* atts = (const float*)d_in[10];
    const float* hb   = (const float*)d_in[11];
    float* out = (float*)d_out;

    const int N  = in_sizes[0] / 256;
    const int E  = in_sizes[1] / 2;
    const int E2 = E + N;

    char* p = (char*)d_ws;
    auto carve = [&](size_t bytes) -> char* {
        char* r = p;
        p += (bytes + 255) & ~(size_t)255;
        return r;
    };
    float* h1      = (float*)carve((size_t)N * HC * 4);
    float* hbuf    = (float*)carve((size_t)N * HC * 4);
    float* zbuf    = (float*)carve((size_t)N * HC * 4);
    float* a_e     = (float*)carve((size_t)E2 * NH * 4);
    float* dinvb   = (float*)carve((size_t)N * NH * 4);
    int* csr_ptr   = (int*)carve((size_t)(N + 1) * 4);
    int* csr_src   = (int*)carve((size_t)E2 * 4);
    int* cursor    = (int*)carve((size_t)N * 4);
    int* partials  = (int*)carve(1024 * 4);

    float decay[5];
    for (int k = 0; k <= 4; ++k) decay[k] = (float)log(1.0 / (k + 1) + 1.0 + 1e-6);

    // ---- CSR build (by destination col) ----
    hipMemsetAsync(cursor, 0, (size_t)N * 4, stream);
    int eb = (E2 + 255) / 256;
    int nb = (N + 255) / 256;
    count_kernel<<<eb, 256, 0, stream>>>(ei, cursor, E, E2);
    scan1_kernel<<<nb, 256, 0, stream>>>(cursor, csr_ptr, partials, N);
    scan2_kernel<<<1, 256, 0, stream>>>(partials, nb);
    scan3_kernel<<<nb, 256, 0, stream>>>(csr_ptr, partials, N, E2);
    hipMemsetAsync(cursor, 0, (size_t)N * 4, stream);
    fill_kernel<<<eb, 256, 0, stream>>>(ei, csr_ptr, cursor, csr_src, E, E2);

    // ---- MLP ----
    int gb = (N + 127) / 128;
    mlp_gemm<256, true ><<<gb, 256, 0, stream>>>(x,  W0, b0, h1,   N);
    mlp_gemm<128, false><<<gb, 256, 0, stream>>>(h1, W1, b1, hbuf, N);

    // ---- hop 0 ----
    hop0_kernel<<<(N * NH + 255) / 256, 256, 0, stream>>>(hbuf, att0, hb, zbuf, N);

    // ---- hops 1..4 ----
    float* hin  = hbuf;
    float* hout = h1;
    int wb = (N + 3) / 4;   // 4 waves (nodes) per 256-thread block
    for (int k = 1; k <= 4; ++k) {
        passA_kernel<<<wb, 256, 0, stream>>>(zbuf, csr_ptr, csr_src,
                                             atts + (size_t)(k - 1) * NH * NC,
                                             decay[k - 1], a_e, dinvb, N);
        passB_kernel<<<wb, 256, 0, stream>>>(hin, zbuf, csr_ptr, csr_src, a_e, dinvb,
                                             hatts + (size_t)(k - 1) * NH * 32,
                                             hb + (size_t)k * NH, decay[k - 1], hout, N,
                                             (k < 4) ? 1 : 0);
        float* t = hin; hin = hout; hout = t;
    }

    // ---- classifier ----
    gout_kernel<<<(N + 63) / 64, 256, 0, stream>>>(zbuf, Wout, bout, out, N);
}

// Round 5
// 857.649 us; speedup vs baseline: 1.8801x; 1.0207x over previous
//
#include <hip/hip_runtime.h>
#include <math.h>

#define NH 8
#define NC 16
#define HC 128

// Fast transcendentals: v_exp_f32 / v_log_f32 hardware paths (~1 ulp).
__device__ __forceinline__ float eluf(float x) { return x > 0.f ? x : __expf(x) - 1.f; }
__device__ __forceinline__ float splusf(float x) { return fmaxf(x, 0.f) + __logf(1.f + __expf(-fabsf(x))); }

// ---------------- CSR build ----------------
__global__ void count_kernel(const int* __restrict__ ei, int* __restrict__ cnt, int E, int E2) {
    int e = blockIdx.x * blockDim.x + threadIdx.x;
    if (e >= E2) return;
    int col = (e < E) ? ei[E + e] : (e - E);
    atomicAdd(&cnt[col], 1);
}

__global__ void scan1_kernel(const int* __restrict__ counts, int* __restrict__ ptr,
                             int* __restrict__ partials, int n) {
    __shared__ int tmp[256];
    int t = threadIdx.x;
    int i = blockIdx.x * 256 + t;
    int v = (i < n) ? counts[i] : 0;
    tmp[t] = v;
    __syncthreads();
    for (int off = 1; off < 256; off <<= 1) {
        int add = (t >= off) ? tmp[t - off] : 0;
        __syncthreads();
        tmp[t] += add;
        __syncthreads();
    }
    if (i < n) ptr[i] = tmp[t] - v;            // block-local exclusive
    if (t == 255) partials[blockIdx.x] = tmp[255];
}

__global__ void scan2_kernel(int* __restrict__ partials, int nb) {
    __shared__ int tmp[256];
    int t = threadIdx.x;
    int v = (t < nb) ? partials[t] : 0;
    tmp[t] = v;
    __syncthreads();
    for (int off = 1; off < 256; off <<= 1) {
        int add = (t >= off) ? tmp[t - off] : 0;
        __syncthreads();
        tmp[t] += add;
        __syncthreads();
    }
    if (t < nb) partials[t] = tmp[t] - v;      // exclusive
}

__global__ void scan3_kernel(int* __restrict__ ptr, const int* __restrict__ partials,
                             int n, int total) {
    int i = blockIdx.x * 256 + threadIdx.x;
    if (i < n) ptr[i] += partials[blockIdx.x];
    if (i == 0) ptr[n] = total;
}

__global__ void fill_kernel(const int* __restrict__ ei, const int* __restrict__ ptr,
                            int* __restrict__ cursor, int* __restrict__ src, int E, int E2) {
    int e = blockIdx.x * blockDim.x + threadIdx.x;
    if (e >= E2) return;
    int col, row;
    if (e < E) { row = ei[e]; col = ei[E + e]; }
    else       { row = e - E; col = e - E; }
    int pos = ptr[col] + atomicAdd(&cursor[col], 1);
    src[pos] = row;
}

// ---------------- fp32 GEMM: out[M x 128] = act(A[M x K] @ W[K x 128] + b) -------------
// HOP0: additionally compute hop-0 attention g per (row, head) and write z = out * g.
template<int K, bool ELU_OUT, bool HOP0>
__global__ __launch_bounds__(256)
void mlp_gemm(const float* __restrict__ A, const float* __restrict__ W,
              const float* __restrict__ bias, float* __restrict__ out, int M,
              float* __restrict__ z_out, const float* __restrict__ att0,
              const float* __restrict__ hb0) {
    __shared__ float As[16][132];   // [k][m], padded
    __shared__ float Ws[16][128];   // [k][n]
    const int tid = threadIdx.x;
    const int m0 = blockIdx.x * 128;
    const int tm = tid >> 4;        // 0..15
    const int tn = tid & 15;        // 0..15
    float acc[8][8];
#pragma unroll
    for (int i = 0; i < 8; ++i)
#pragma unroll
        for (int j = 0; j < 8; ++j) acc[i][j] = 0.f;

    const int ra = tid >> 1;            // 0..127 (A tile row)
    const int ha = (tid & 1) * 8;       // k-offset half
    const int rw = tid >> 4;            // 0..15 (W tile row)
    const int cw = (tid & 15) * 8;      // W col

    for (int k0 = 0; k0 < K; k0 += 16) {
        float4 a0 = make_float4(0.f, 0.f, 0.f, 0.f), a1 = a0;
        int garow = m0 + ra;
        if (garow < M) {
            const float* ap = A + (size_t)garow * K + k0 + ha;
            a0 = *(const float4*)(ap);
            a1 = *(const float4*)(ap + 4);
        }
        const float* wp = W + (size_t)(k0 + rw) * 128 + cw;
        float4 w0 = *(const float4*)(wp);
        float4 w1 = *(const float4*)(wp + 4);
        __syncthreads();
        As[ha + 0][ra] = a0.x; As[ha + 1][ra] = a0.y; As[ha + 2][ra] = a0.z; As[ha + 3][ra] = a0.w;
        As[ha + 4][ra] = a1.x; As[ha + 5][ra] = a1.y; As[ha + 6][ra] = a1.z; As[ha + 7][ra] = a1.w;
        *(float4*)&Ws[rw][cw]     = w0;
        *(float4*)&Ws[rw][cw + 4] = w1;
        __syncthreads();
#pragma unroll
        for (int kk = 0; kk < 16; ++kk) {
            float ar[8], wr[8];
            *(float4*)&ar[0] = *(const float4*)&As[kk][tm * 8];
            *(float4*)&ar[4] = *(const float4*)&As[kk][tm * 8 + 4];
            *(float4*)&wr[0] = *(const float4*)&Ws[kk][tn * 8];
            *(float4*)&wr[4] = *(const float4*)&Ws[kk][tn * 8 + 4];
#pragma unroll
            for (int i = 0; i < 8; ++i)
#pragma unroll
                for (int j = 0; j < 8; ++j)
                    acc[i][j] = fmaf(ar[i], wr[j], acc[i][j]);
        }
    }
#pragma unroll
    for (int i = 0; i < 8; ++i) {
        int r = m0 + tm * 8 + i;
        float vv[8];
#pragma unroll
        for (int j = 0; j < 8; ++j) {
            float v = acc[i][j] + bias[tn * 8 + j];
            if (ELU_OUT) v = eluf(v);
            vv[j] = v;
        }
        if (HOP0) {
            // g[r][hd] = hb0[hd] + sum_c att0[hd*16+c]*elu(h[r][c]);
            // this thread's 8 cols are att0-flat indices tn*8..tn*8+7;
            // partner lane (tn^1, same tm => lane^1) holds the head's other 8.
            float part = 0.f;
#pragma unroll
            for (int j = 0; j < 8; ++j)
                part += att0[tn * 8 + j] * eluf(vv[j]);
            part += __shfl_xor(part, 1);
            float g = part + hb0[tn >> 1];
            if (r < M) {
                float* op = out + (size_t)r * 128 + tn * 8;
                float* zp = z_out + (size_t)r * 128 + tn * 8;
#pragma unroll
                for (int j = 0; j < 8; ++j) {
                    op[j] = vv[j];
                    zp[j] = vv[j] * g;
                }
            }
        } else {
            if (r < M) {
                float* op = out + (size_t)r * 128 + tn * 8;
#pragma unroll
                for (int j = 0; j < 8; ++j) op[j] = vv[j];
            }
        }
    }
}

// ---------------- pass A: edge attention + degree + dinv (fused) ----------------
// One wave per node; 2 edges in flight (one per 32-lane half) x unroll-4
// => 8 independent 512 B row gathers outstanding per wave.
// Lane = (half, q): q covers channels 4q..4q+3 via float4; head = q>>2.
__global__ __launch_bounds__(256)
void passA_kernel(const float* __restrict__ z, const int* __restrict__ ptr,
                  const int* __restrict__ src, const float* __restrict__ att,
                  float decay, float* __restrict__ a_e, float* __restrict__ dinv, int n) {
    int wid = (int)((blockIdx.x * 256u + threadIdx.x) >> 6);
    if (wid >= n) return;
    const int lane = threadIdx.x & 63;
    const int half = lane >> 5;       // which of 2 concurrent edges
    const int q    = lane & 31;       // channel quad
    const int hd   = q >> 2;          // head
    const unsigned i = (unsigned)wid;

    float4 zi = *(const float4*)(z + (i << 7) + (q << 2));
    zi.x *= decay; zi.y *= decay; zi.z *= decay; zi.w *= decay;
    const float4 av = *(const float4*)(att + (q << 2));

    int s0 = ptr[wid], s1 = ptr[wid + 1];
    float dacc = 0.f;
    int s = s0 + half;
    for (; s + 6 < s1; s += 8) {
        unsigned j0 = (unsigned)src[s];
        unsigned j1 = (unsigned)src[s + 2];
        unsigned j2 = (unsigned)src[s + 4];
        unsigned j3 = (unsigned)src[s + 6];
        const float4 r0 = *(const float4*)(z + (j0 << 7) + (q << 2));
        const float4 r1 = *(const float4*)(z + (j1 << 7) + (q << 2));
        const float4 r2 = *(const float4*)(z + (j2 << 7) + (q << 2));
        const float4 r3 = *(const float4*)(z + (j3 << 7) + (q << 2));
        float p0, p1, p2, p3;
        p0  = av.x * eluf(fmaf(r0.x, decay, zi.x));
        p0 += av.y * eluf(fmaf(r0.y, decay, zi.y));
        p0 += av.z * eluf(fmaf(r0.z, decay, zi.z));
        p0 += av.w * eluf(fmaf(r0.w, decay, zi.w));
        p1  = av.x * eluf(fmaf(r1.x, decay, zi.x));
        p1 += av.y * eluf(fmaf(r1.y, decay, zi.y));
        p1 += av.z * eluf(fmaf(r1.z, decay, zi.z));
        p1 += av.w * eluf(fmaf(r1.w, decay, zi.w));
        p2  = av.x * eluf(fmaf(r2.x, decay, zi.x));
        p2 += av.y * eluf(fmaf(r2.y, decay, zi.y));
        p2 += av.z * eluf(fmaf(r2.z, decay, zi.z));
        p2 += av.w * eluf(fmaf(r2.w, decay, zi.w));
        p3  = av.x * eluf(fmaf(r3.x, decay, zi.x));
        p3 += av.y * eluf(fmaf(r3.y, decay, zi.y));
        p3 += av.z * eluf(fmaf(r3.z, decay, zi.z));
        p3 += av.w * eluf(fmaf(r3.w, decay, zi.w));
        p0 += __shfl_xor(p0, 1); p1 += __shfl_xor(p1, 1);
        p2 += __shfl_xor(p2, 1); p3 += __shfl_xor(p3, 1);
        p0 += __shfl_xor(p0, 2); p1 += __shfl_xor(p1, 2);
        p2 += __shfl_xor(p2, 2); p3 += __shfl_xor(p3, 2);
        if ((q & 3) == 0) {
            float a0 = splusf(p0) + 1e-6f;
            float a1 = splusf(p1) + 1e-6f;
            float a2 = splusf(p2) + 1e-6f;
            float a3 = splusf(p3) + 1e-6f;
            a_e[((unsigned)s << 3) + hd] = a0;
            a_e[((unsigned)(s + 2) << 3) + hd] = a1;
            a_e[((unsigned)(s + 4) << 3) + hd] = a2;
            a_e[((unsigned)(s + 6) << 3) + hd] = a3;
            dacc += (a0 + a1) + (a2 + a3);
        }
    }
    for (; s < s1; s += 2) {
        unsigned j = (unsigned)src[s];
        const float4 r = *(const float4*)(z + (j << 7) + (q << 2));
        float p;
        p  = av.x * eluf(fmaf(r.x, decay, zi.x));
        p += av.y * eluf(fmaf(r.y, decay, zi.y));
        p += av.z * eluf(fmaf(r.z, decay, zi.z));
        p += av.w * eluf(fmaf(r.w, decay, zi.w));
        p += __shfl_xor(p, 1);
        p += __shfl_xor(p, 2);
        if ((q & 3) == 0) {
            float aval = splusf(p) + 1e-6f;
            a_e[((unsigned)s << 3) + hd] = aval;
            dacc += aval;
        }
    }
    dacc += __shfl_xor(dacc, 32);
    if (half == 0 && (q & 3) == 0) {
        dinv[(i << 3) + hd] = (dacc > 0.f) ? (1.f / sqrtf(dacc)) : 0.f;
    }
}

// ---------------- pass B: propagate + hop attention + z update ----------------
// Same half-wave layout as passA: 2 edges in flight x unroll-4.
__global__ __launch_bounds__(256)
void passB_kernel(const float* __restrict__ h_in, float* __restrict__ z,
                  const int* __restrict__ ptr, const int* __restrict__ src,
                  const float* __restrict__ a_e, const float* __restrict__ dinv,
                  const float* __restrict__ hatt, const float* __restrict__ hb,
                  float decay, float* __restrict__ h_out, int n, int store_h) {
    int wid = (int)((blockIdx.x * 256u + threadIdx.x) >> 6);
    if (wid >= n) return;
    const int lane = threadIdx.x & 63;
    const int half = lane >> 5;
    const int q    = lane & 31;
    const int hd   = q >> 2;
    const unsigned i = (unsigned)wid;

    const float di = dinv[(i << 3) + hd];
    int s0 = ptr[wid], s1 = ptr[wid + 1];
    float ax = 0.f, ay = 0.f, az = 0.f, aw = 0.f;
    int s = s0 + half;
    for (; s + 6 < s1; s += 8) {
        unsigned j0 = (unsigned)src[s];
        unsigned j1 = (unsigned)src[s + 2];
        unsigned j2 = (unsigned)src[s + 4];
        unsigned j3 = (unsigned)src[s + 6];
        float w0 = a_e[((unsigned)s << 3) + hd]       * dinv[(j0 << 3) + hd];
        float w1 = a_e[((unsigned)(s + 2) << 3) + hd] * dinv[(j1 << 3) + hd];
        float w2 = a_e[((unsigned)(s + 4) << 3) + hd] * dinv[(j2 << 3) + hd];
        float w3 = a_e[((unsigned)(s + 6) << 3) + hd] * dinv[(j3 << 3) + hd];
        const float4 f0 = *(const float4*)(h_in + (j0 << 7) + (q << 2));
        const float4 f1 = *(const float4*)(h_in + (j1 << 7) + (q << 2));
        const float4 f2 = *(const float4*)(h_in + (j2 << 7) + (q << 2));
        const float4 f3 = *(const float4*)(h_in + (j3 << 7) + (q << 2));
        ax = fmaf(w0, f0.x, ax); ay = fmaf(w0, f0.y, ay);
        az = fmaf(w0, f0.z, az); aw = fmaf(w0, f0.w, aw);
        ax = fmaf(w1, f1.x, ax); ay = fmaf(w1, f1.y, ay);
        az = fmaf(w1, f1.z, az); aw = fmaf(w1, f1.w, aw);
        ax = fmaf(w2, f2.x, ax); ay = fmaf(w2, f2.y, ay);
        az = fmaf(w2, f2.z, az); aw = fmaf(w2, f2.w, aw);
        ax = fmaf(w3, f3.x, ax); ay = fmaf(w3, f3.y, ay);
        az = fmaf(w3, f3.z, az); aw = fmaf(w3, f3.w, aw);
    }
    for (; s < s1; s += 2) {
        unsigned j = (unsigned)src[s];
        float w = a_e[((unsigned)s << 3) + hd] * dinv[(j << 3) + hd];
        const float4 f = *(const float4*)(h_in + (j << 7) + (q << 2));
        ax = fmaf(w, f.x, ax); ay = fmaf(w, f.y, ay);
        az = fmaf(w, f.z, az); aw = fmaf(w, f.w, aw);
    }
    // combine the two halves (each accumulated a disjoint set of edges)
    ax += __shfl_xor(ax, 32);
    ay += __shfl_xor(ay, 32);
    az += __shfl_xor(az, 32);
    aw += __shfl_xor(aw, 32);

    const float4 hn = make_float4(di * ax, di * ay, di * az, di * aw);
    const float4 zv = *(const float4*)(z + (i << 7) + (q << 2));
    const float* hA = hatt + hd * 32 + ((q & 3) << 2);
    float p;
    p  = hA[0] * eluf(hn.x) + hA[1] * eluf(hn.y)
       + hA[2] * eluf(hn.z) + hA[3] * eluf(hn.w);
    p += hA[16] * eluf(zv.x * decay) + hA[17] * eluf(zv.y * decay)
       + hA[18] * eluf(zv.z * decay) + hA[19] * eluf(zv.w * decay);
    p += __shfl_xor(p, 1);
    p += __shfl_xor(p, 2);
    const float g = p + hb[hd];
    if (half == 0) {
        if (store_h)
            *(float4*)(h_out + (i << 7) + (q << 2)) = hn;
        *(float4*)(z + (i << 7) + (q << 2)) =
            make_float4(zv.x + hn.x * g, zv.y + hn.y * g,
                        zv.z + hn.z * g, zv.w + hn.w * g);
    }
}

// ---------------- output GEMM: out[M x 40] = elu(z)[M x 128] @ Wout + bout --------------
__global__ __launch_bounds__(256)
void gout_kernel(const float* __restrict__ z, const float* __restrict__ W,
                 const float* __restrict__ bias, float* __restrict__ out, int M) {
    __shared__ float zs[128 * 65];   // [k][r], stride 65
    __shared__ float ws[128 * 40];   // [k][n]
    const int tid = threadIdx.x;
    const int r0 = blockIdx.x * 64;
    for (int idx = tid; idx < 128 * 40; idx += 256) ws[idx] = W[idx];
    const int r = tid >> 2;   // 0..63
    const int q = tid & 3;    // 0..3
    {
        int grow = r0 + r;
#pragma unroll
        for (int t = 0; t < 8; ++t) {
            int k = q * 4 + t * 16;
            float4 v = make_float4(0.f, 0.f, 0.f, 0.f);
            if (grow < M) v = *(const float4*)(z + (size_t)grow * HC + k);
            zs[(k + 0) * 65 + r] = eluf(v.x);
            zs[(k + 1) * 65 + r] = eluf(v.y);
            zs[(k + 2) * 65 + r] = eluf(v.z);
            zs[(k + 3) * 65 + r] = eluf(v.w);
        }
    }
    __syncthreads();
    float acc[10];
#pragma unroll
    for (int j = 0; j < 10; ++j) acc[j] = bias[q * 10 + j];
    for (int k = 0; k < 128; ++k) {
        float zk = zs[k * 65 + r];
#pragma unroll
        for (int j = 0; j < 10; ++j)
            acc[j] = fmaf(zk, ws[k * 40 + q * 10 + j], acc[j]);
    }
    int grow = r0 + r;
    if (grow < M) {
        float* op = out + (size_t)grow * 40 + q * 10;
#pragma unroll
        for (int j = 0; j < 10; ++j) op[j] = acc[j];
    }
}

extern "C" void kernel_launch(void* const* d_in, const int* in_sizes, int n_in,
                              void* d_out, int out_size, void* d_ws, size_t ws_size,
                              hipStream_t stream) {
    (void)n_in; (void)out_size; (void)ws_size;
    const float* x    = (const float*)d_in[0];
    const int*   ei   = (const int*)d_in[1];
    const float* W0   = (const float*)d_in[2];
    const float* b0   = (const float*)d_in[3];
    const float* W1   = (const float*)d_in[4];
    const float* b1   = (const float*)d_in[5];
    const float* Wout = (const float*)d_in[6];
    const float* bout = (const float*)d_in[7];
    const float* att0 = (const float*)d_in[8];
    const float* hatts= (const float*)d_in[9];
    const float* atts = (const float*)d_in[10];
    const float* hb   = (const float*)d_in[11];
    float* out = (float*)d_out;

    const int N  = in_sizes[0] / 256;
    const int E  = in_sizes[1] / 2;
    const int E2 = E + N;

    char* p = (char*)d_ws;
    auto carve = [&](size_t bytes) -> char* {
        char* r = p;
        p += (bytes + 255) & ~(size_t)255;
        return r;
    };
    float* h1      = (float*)carve((size_t)N * HC * 4);
    float* hbuf    = (float*)carve((size_t)N * HC * 4);
    float* zbuf    = (float*)carve((size_t)N * HC * 4);
    float* a_e     = (float*)carve((size_t)E2 * NH * 4);
    float* dinvb   = (float*)carve((size_t)N * NH * 4);
    int* csr_ptr   = (int*)carve((size_t)(N + 1) * 4);
    int* csr_src   = (int*)carve((size_t)E2 * 4);
    int* cursor    = (int*)carve((size_t)N * 4);
    int* partials  = (int*)carve(1024 * 4);

    float decay[5];
    for (int k = 0; k <= 4; ++k) decay[k] = (float)log(1.0 / (k + 1) + 1.0 + 1e-6);

    // ---- CSR build (by destination col) ----
    hipMemsetAsync(cursor, 0, (size_t)N * 4, stream);
    int eb = (E2 + 255) / 256;
    int nb = (N + 255) / 256;
    count_kernel<<<eb, 256, 0, stream>>>(ei, cursor, E, E2);
    scan1_kernel<<<nb, 256, 0, stream>>>(cursor, csr_ptr, partials, N);
    scan2_kernel<<<1, 256, 0, stream>>>(partials, nb);
    scan3_kernel<<<nb, 256, 0, stream>>>(csr_ptr, partials, N, E2);
    hipMemsetAsync(cursor, 0, (size_t)N * 4, stream);
    fill_kernel<<<eb, 256, 0, stream>>>(ei, csr_ptr, cursor, csr_src, E, E2);

    // ---- MLP (hop-0 attention fused into gemm2 epilogue) ----
    int gb = (N + 127) / 128;
    mlp_gemm<256, true , false><<<gb, 256, 0, stream>>>(x,  W0, b0, h1,   N,
                                                        nullptr, nullptr, nullptr);
    mlp_gemm<128, false, true ><<<gb, 256, 0, stream>>>(h1, W1, b1, hbuf, N,
                                                        zbuf, att0, hb);

    // ---- hops 1..4 ----
    float* hin  = hbuf;
    float* hout = h1;
    int wb = (N + 3) / 4;   // 4 waves (nodes) per 256-thread block
    for (int k = 1; k <= 4; ++k) {
        passA_kernel<<<wb, 256, 0, stream>>>(zbuf, csr_ptr, csr_src,
                                             atts + (size_t)(k - 1) * NH * NC,
                                             decay[k - 1], a_e, dinvb, N);
        passB_kernel<<<wb, 256, 0, stream>>>(hin, zbuf, csr_ptr, csr_src, a_e, dinvb,
                                             hatts + (size_t)(k - 1) * NH * 32,
                                             hb + (size_t)k * NH, decay[k - 1], hout, N,
                                             (k < 4) ? 1 : 0);
        float* t = hin; hin = hout; hout = t;
    }

    // ---- classifier ----
    gout_kernel<<<(N + 63) / 64, 256, 0, stream>>>(zbuf, Wout, bout, out, N);
}

// Round 6
// 738.254 us; speedup vs baseline: 2.1841x; 1.1617x over previous
//
#include <hip/hip_runtime.h>
#include <hip/hip_fp16.h>
#include <math.h>

#define NH 8
#define NC 16
#define HC 128

typedef __attribute__((ext_vector_type(4))) _Float16 half4;

// Fast transcendentals: v_exp_f32 / v_log_f32 hardware paths (~1 ulp).
__device__ __forceinline__ float eluf(float x) { return x > 0.f ? x : __expf(x) - 1.f; }
__device__ __forceinline__ float splusf(float x) { return fmaxf(x, 0.f) + __logf(1.f + __expf(-fabsf(x))); }

// ---------------- CSR build ----------------
__global__ void count_kernel(const int* __restrict__ ei, int* __restrict__ cnt, int E, int E2) {
    int e = blockIdx.x * blockDim.x + threadIdx.x;
    if (e >= E2) return;
    int col = (e < E) ? ei[E + e] : (e - E);
    atomicAdd(&cnt[col], 1);
}

__global__ void scan1_kernel(const int* __restrict__ counts, int* __restrict__ ptr,
                             int* __restrict__ partials, int n) {
    __shared__ int tmp[256];
    int t = threadIdx.x;
    int i = blockIdx.x * 256 + t;
    int v = (i < n) ? counts[i] : 0;
    tmp[t] = v;
    __syncthreads();
    for (int off = 1; off < 256; off <<= 1) {
        int add = (t >= off) ? tmp[t - off] : 0;
        __syncthreads();
        tmp[t] += add;
        __syncthreads();
    }
    if (i < n) ptr[i] = tmp[t] - v;            // block-local exclusive
    if (t == 255) partials[blockIdx.x] = tmp[255];
}

__global__ void scan2_kernel(int* __restrict__ partials, int nb) {
    __shared__ int tmp[256];
    int t = threadIdx.x;
    int v = (t < nb) ? partials[t] : 0;
    tmp[t] = v;
    __syncthreads();
    for (int off = 1; off < 256; off <<= 1) {
        int add = (t >= off) ? tmp[t - off] : 0;
        __syncthreads();
        tmp[t] += add;
        __syncthreads();
    }
    if (t < nb) partials[t] = tmp[t] - v;      // exclusive
}

__global__ void scan3_kernel(int* __restrict__ ptr, const int* __restrict__ partials,
                             int n, int total) {
    int i = blockIdx.x * 256 + threadIdx.x;
    if (i < n) ptr[i] += partials[blockIdx.x];
    if (i == 0) ptr[n] = total;
}

__global__ void fill_kernel(const int* __restrict__ ei, const int* __restrict__ ptr,
                            int* __restrict__ cursor, int* __restrict__ src, int E, int E2) {
    int e = blockIdx.x * blockDim.x + threadIdx.x;
    if (e >= E2) return;
    int col, row;
    if (e < E) { row = ei[e]; col = ei[E + e]; }
    else       { row = e - E; col = e - E; }
    int pos = ptr[col] + atomicAdd(&cursor[col], 1);
    src[pos] = row;
}

// ---------------- fp32 GEMM: out[M x 128] = act(A[M x K] @ W[K x 128] + b) -------------
// HOP0: additionally compute hop-0 attention g per (row, head), write z = out * g (fp32)
// and h as fp16 (propagate operand for passB).
template<int K, bool ELU_OUT, bool HOP0>
__global__ __launch_bounds__(256)
void mlp_gemm(const float* __restrict__ A, const float* __restrict__ W,
              const float* __restrict__ bias, float* __restrict__ out, int M,
              float* __restrict__ z_out, _Float16* __restrict__ h16_out,
              const float* __restrict__ att0, const float* __restrict__ hb0) {
    __shared__ float As[16][132];   // [k][m], padded
    __shared__ float Ws[16][128];   // [k][n]
    const int tid = threadIdx.x;
    const int m0 = blockIdx.x * 128;
    const int tm = tid >> 4;        // 0..15
    const int tn = tid & 15;        // 0..15
    float acc[8][8];
#pragma unroll
    for (int i = 0; i < 8; ++i)
#pragma unroll
        for (int j = 0; j < 8; ++j) acc[i][j] = 0.f;

    const int ra = tid >> 1;            // 0..127 (A tile row)
    const int ha = (tid & 1) * 8;       // k-offset half
    const int rw = tid >> 4;            // 0..15 (W tile row)
    const int cw = (tid & 15) * 8;      // W col

    for (int k0 = 0; k0 < K; k0 += 16) {
        float4 a0 = make_float4(0.f, 0.f, 0.f, 0.f), a1 = a0;
        int garow = m0 + ra;
        if (garow < M) {
            const float* ap = A + (size_t)garow * K + k0 + ha;
            a0 = *(const float4*)(ap);
            a1 = *(const float4*)(ap + 4);
        }
        const float* wp = W + (size_t)(k0 + rw) * 128 + cw;
        float4 w0 = *(const float4*)(wp);
        float4 w1 = *(const float4*)(wp + 4);
        __syncthreads();
        As[ha + 0][ra] = a0.x; As[ha + 1][ra] = a0.y; As[ha + 2][ra] = a0.z; As[ha + 3][ra] = a0.w;
        As[ha + 4][ra] = a1.x; As[ha + 5][ra] = a1.y; As[ha + 6][ra] = a1.z; As[ha + 7][ra] = a1.w;
        *(float4*)&Ws[rw][cw]     = w0;
        *(float4*)&Ws[rw][cw + 4] = w1;
        __syncthreads();
#pragma unroll
        for (int kk = 0; kk < 16; ++kk) {
            float ar[8], wr[8];
            *(float4*)&ar[0] = *(const float4*)&As[kk][tm * 8];
            *(float4*)&ar[4] = *(const float4*)&As[kk][tm * 8 + 4];
            *(float4*)&wr[0] = *(const float4*)&Ws[kk][tn * 8];
            *(float4*)&wr[4] = *(const float4*)&Ws[kk][tn * 8 + 4];
#pragma unroll
            for (int i = 0; i < 8; ++i)
#pragma unroll
                for (int j = 0; j < 8; ++j)
                    acc[i][j] = fmaf(ar[i], wr[j], acc[i][j]);
        }
    }
#pragma unroll
    for (int i = 0; i < 8; ++i) {
        int r = m0 + tm * 8 + i;
        float vv[8];
#pragma unroll
        for (int j = 0; j < 8; ++j) {
            float v = acc[i][j] + bias[tn * 8 + j];
            if (ELU_OUT) v = eluf(v);
            vv[j] = v;
        }
        if (HOP0) {
            // g[r][hd] = hb0[hd] + sum_c att0[hd*16+c]*elu(h[r][c]);
            // this thread's 8 cols are att0-flat indices tn*8..tn*8+7;
            // partner lane (lane^1) holds the head's other 8.
            float part = 0.f;
#pragma unroll
            for (int j = 0; j < 8; ++j)
                part += att0[tn * 8 + j] * eluf(vv[j]);
            part += __shfl_xor(part, 1);
            float g = part + hb0[tn >> 1];
            if (r < M) {
                _Float16* hp = h16_out + (size_t)r * 128 + tn * 8;
                float* zp = z_out + (size_t)r * 128 + tn * 8;
                half4 h0, h1;
                h0.x = (_Float16)vv[0]; h0.y = (_Float16)vv[1];
                h0.z = (_Float16)vv[2]; h0.w = (_Float16)vv[3];
                h1.x = (_Float16)vv[4]; h1.y = (_Float16)vv[5];
                h1.z = (_Float16)vv[6]; h1.w = (_Float16)vv[7];
                *(half4*)(hp)     = h0;
                *(half4*)(hp + 4) = h1;
#pragma unroll
                for (int j = 0; j < 8; ++j) zp[j] = vv[j] * g;
            }
        } else {
            if (r < M) {
                float* op = out + (size_t)r * 128 + tn * 8;
#pragma unroll
                for (int j = 0; j < 8; ++j) op[j] = vv[j];
            }
        }
    }
}

// ---------------- pass A: edge attention + degree + dinv (fused) ----------------
// One wave per node; 2 edges in flight (one per 32-lane half) x unroll-4.
// Lane = (half, q): q covers channels 4q..4q+3 via float4; head = q>>2.
// z gathered fp32 (z has O(100) dynamic range in hub rows); a_e stored fp16.
__global__ __launch_bounds__(256)
void passA_kernel(const float* __restrict__ z, const int* __restrict__ ptr,
                  const int* __restrict__ src, const float* __restrict__ att,
                  float decay, _Float16* __restrict__ a_e, float* __restrict__ dinv, int n) {
    int wid = (int)((blockIdx.x * 256u + threadIdx.x) >> 6);
    if (wid >= n) return;
    const int lane = threadIdx.x & 63;
    const int half = lane >> 5;       // which of 2 concurrent edges
    const int q    = lane & 31;       // channel quad
    const int hd   = q >> 2;          // head
    const unsigned i = (unsigned)wid;

    float4 zi = *(const float4*)(z + (i << 7) + (q << 2));
    zi.x *= decay; zi.y *= decay; zi.z *= decay; zi.w *= decay;
    const float4 av = *(const float4*)(att + (q << 2));

    int s0 = ptr[wid], s1 = ptr[wid + 1];
    float dacc = 0.f;
    int s = s0 + half;
    for (; s + 6 < s1; s += 8) {
        unsigned j0 = (unsigned)src[s];
        unsigned j1 = (unsigned)src[s + 2];
        unsigned j2 = (unsigned)src[s + 4];
        unsigned j3 = (unsigned)src[s + 6];
        const float4 r0 = *(const float4*)(z + (j0 << 7) + (q << 2));
        const float4 r1 = *(const float4*)(z + (j1 << 7) + (q << 2));
        const float4 r2 = *(const float4*)(z + (j2 << 7) + (q << 2));
        const float4 r3 = *(const float4*)(z + (j3 << 7) + (q << 2));
        float p0, p1, p2, p3;
        p0  = av.x * eluf(fmaf(r0.x, decay, zi.x));
        p0 += av.y * eluf(fmaf(r0.y, decay, zi.y));
        p0 += av.z * eluf(fmaf(r0.z, decay, zi.z));
        p0 += av.w * eluf(fmaf(r0.w, decay, zi.w));
        p1  = av.x * eluf(fmaf(r1.x, decay, zi.x));
        p1 += av.y * eluf(fmaf(r1.y, decay, zi.y));
        p1 += av.z * eluf(fmaf(r1.z, decay, zi.z));
        p1 += av.w * eluf(fmaf(r1.w, decay, zi.w));
        p2  = av.x * eluf(fmaf(r2.x, decay, zi.x));
        p2 += av.y * eluf(fmaf(r2.y, decay, zi.y));
        p2 += av.z * eluf(fmaf(r2.z, decay, zi.z));
        p2 += av.w * eluf(fmaf(r2.w, decay, zi.w));
        p3  = av.x * eluf(fmaf(r3.x, decay, zi.x));
        p3 += av.y * eluf(fmaf(r3.y, decay, zi.y));
        p3 += av.z * eluf(fmaf(r3.z, decay, zi.z));
        p3 += av.w * eluf(fmaf(r3.w, decay, zi.w));
        p0 += __shfl_xor(p0, 1); p1 += __shfl_xor(p1, 1);
        p2 += __shfl_xor(p2, 1); p3 += __shfl_xor(p3, 1);
        p0 += __shfl_xor(p0, 2); p1 += __shfl_xor(p1, 2);
        p2 += __shfl_xor(p2, 2); p3 += __shfl_xor(p3, 2);
        if ((q & 3) == 0) {
            float a0 = splusf(p0) + 1e-6f;
            float a1 = splusf(p1) + 1e-6f;
            float a2 = splusf(p2) + 1e-6f;
            float a3 = splusf(p3) + 1e-6f;
            a_e[((unsigned)s << 3) + hd] = (_Float16)a0;
            a_e[((unsigned)(s + 2) << 3) + hd] = (_Float16)a1;
            a_e[((unsigned)(s + 4) << 3) + hd] = (_Float16)a2;
            a_e[((unsigned)(s + 6) << 3) + hd] = (_Float16)a3;
            dacc += (a0 + a1) + (a2 + a3);
        }
    }
    for (; s < s1; s += 2) {
        unsigned j = (unsigned)src[s];
        const float4 r = *(const float4*)(z + (j << 7) + (q << 2));
        float p;
        p  = av.x * eluf(fmaf(r.x, decay, zi.x));
        p += av.y * eluf(fmaf(r.y, decay, zi.y));
        p += av.z * eluf(fmaf(r.z, decay, zi.z));
        p += av.w * eluf(fmaf(r.w, decay, zi.w));
        p += __shfl_xor(p, 1);
        p += __shfl_xor(p, 2);
        if ((q & 3) == 0) {
            float aval = splusf(p) + 1e-6f;
            a_e[((unsigned)s << 3) + hd] = (_Float16)aval;
            dacc += aval;
        }
    }
    dacc += __shfl_xor(dacc, 32);
    if (half == 0 && (q & 3) == 0) {
        dinv[(i << 3) + hd] = (dacc > 0.f) ? (1.f / sqrtf(dacc)) : 0.f;
    }
}

// ---------------- pass B: propagate + hop attention + z update ----------------
// Same half-wave layout: 2 edges in flight x unroll-4. h gathered/stored fp16.
__global__ __launch_bounds__(256)
void passB_kernel(const _Float16* __restrict__ h_in, float* __restrict__ z,
                  const int* __restrict__ ptr, const int* __restrict__ src,
                  const _Float16* __restrict__ a_e, const float* __restrict__ dinv,
                  const float* __restrict__ hatt, const float* __restrict__ hb,
                  float decay, _Float16* __restrict__ h_out, int n, int store_h) {
    int wid = (int)((blockIdx.x * 256u + threadIdx.x) >> 6);
    if (wid >= n) return;
    const int lane = threadIdx.x & 63;
    const int half = lane >> 5;
    const int q    = lane & 31;
    const int hd   = q >> 2;
    const unsigned i = (unsigned)wid;

    const float di = dinv[(i << 3) + hd];
    int s0 = ptr[wid], s1 = ptr[wid + 1];
    float ax = 0.f, ay = 0.f, az = 0.f, aw = 0.f;
    int s = s0 + half;
    for (; s + 6 < s1; s += 8) {
        unsigned j0 = (unsigned)src[s];
        unsigned j1 = (unsigned)src[s + 2];
        unsigned j2 = (unsigned)src[s + 4];
        unsigned j3 = (unsigned)src[s + 6];
        float w0 = (float)a_e[((unsigned)s << 3) + hd]       * dinv[(j0 << 3) + hd];
        float w1 = (float)a_e[((unsigned)(s + 2) << 3) + hd] * dinv[(j1 << 3) + hd];
        float w2 = (float)a_e[((unsigned)(s + 4) << 3) + hd] * dinv[(j2 << 3) + hd];
        float w3 = (float)a_e[((unsigned)(s + 6) << 3) + hd] * dinv[(j3 << 3) + hd];
        const half4 f0 = *(const half4*)(h_in + (j0 << 7) + (q << 2));
        const half4 f1 = *(const half4*)(h_in + (j1 << 7) + (q << 2));
        const half4 f2 = *(const half4*)(h_in + (j2 << 7) + (q << 2));
        const half4 f3 = *(const half4*)(h_in + (j3 << 7) + (q << 2));
        ax = fmaf(w0, (float)f0.x, ax); ay = fmaf(w0, (float)f0.y, ay);
        az = fmaf(w0, (float)f0.z, az); aw = fmaf(w0, (float)f0.w, aw);
        ax = fmaf(w1, (float)f1.x, ax); ay = fmaf(w1, (float)f1.y, ay);
        az = fmaf(w1, (float)f1.z, az); aw = fmaf(w1, (float)f1.w, aw);
        ax = fmaf(w2, (float)f2.x, ax); ay = fmaf(w2, (float)f2.y, ay);
        az = fmaf(w2, (float)f2.z, az); aw = fmaf(w2, (float)f2.w, aw);
        ax = fmaf(w3, (float)f3.x, ax); ay = fmaf(w3, (float)f3.y, ay);
        az = fmaf(w3, (float)f3.z, az); aw = fmaf(w3, (float)f3.w, aw);
    }
    for (; s < s1; s += 2) {
        unsigned j = (unsigned)src[s];
        float w = (float)a_e[((unsigned)s << 3) + hd] * dinv[(j << 3) + hd];
        const half4 f = *(const half4*)(h_in + (j << 7) + (q << 2));
        ax = fmaf(w, (float)f.x, ax); ay = fmaf(w, (float)f.y, ay);
        az = fmaf(w, (float)f.z, az); aw = fmaf(w, (float)f.w, aw);
    }
    // combine the two halves (each accumulated a disjoint set of edges)
    ax += __shfl_xor(ax, 32);
    ay += __shfl_xor(ay, 32);
    az += __shfl_xor(az, 32);
    aw += __shfl_xor(aw, 32);

    const float4 hn = make_float4(di * ax, di * ay, di * az, di * aw);
    const float4 zv = *(const float4*)(z + (i << 7) + (q << 2));
    const float* hA = hatt + hd * 32 + ((q & 3) << 2);
    float p;
    p  = hA[0] * eluf(hn.x) + hA[1] * eluf(hn.y)
       + hA[2] * eluf(hn.z) + hA[3] * eluf(hn.w);
    p += hA[16] * eluf(zv.x * decay) + hA[17] * eluf(zv.y * decay)
       + hA[18] * eluf(zv.z * decay) + hA[19] * eluf(zv.w * decay);
    p += __shfl_xor(p, 1);
    p += __shfl_xor(p, 2);
    const float g = p + hb[hd];
    if (half == 0) {
        if (store_h) {
            half4 ho;
            ho.x = (_Float16)hn.x; ho.y = (_Float16)hn.y;
            ho.z = (_Float16)hn.z; ho.w = (_Float16)hn.w;
            *(half4*)(h_out + (i << 7) + (q << 2)) = ho;
        }
        *(float4*)(z + (i << 7) + (q << 2)) =
            make_float4(zv.x + hn.x * g, zv.y + hn.y * g,
                        zv.z + hn.z * g, zv.w + hn.w * g);
    }
}

// ---------------- output GEMM: out[M x 40] = elu(z)[M x 128] @ Wout + bout --------------
__global__ __launch_bounds__(256)
void gout_kernel(const float* __restrict__ z, const float* __restrict__ W,
                 const float* __restrict__ bias, float* __restrict__ out, int M) {
    __shared__ float zs[128 * 65];   // [k][r], stride 65
    __shared__ float ws[128 * 40];   // [k][n]
    const int tid = threadIdx.x;
    const int r0 = blockIdx.x * 64;
    for (int idx = tid; idx < 128 * 40; idx += 256) ws[idx] = W[idx];
    const int r = tid >> 2;   // 0..63
    const int q = tid & 3;    // 0..3
    {
        int grow = r0 + r;
#pragma unroll
        for (int t = 0; t < 8; ++t) {
            int k = q * 4 + t * 16;
            float4 v = make_float4(0.f, 0.f, 0.f, 0.f);
            if (grow < M) v = *(const float4*)(z + (size_t)grow * HC + k);
            zs[(k + 0) * 65 + r] = eluf(v.x);
            zs[(k + 1) * 65 + r] = eluf(v.y);
            zs[(k + 2) * 65 + r] = eluf(v.z);
            zs[(k + 3) * 65 + r] = eluf(v.w);
        }
    }
    __syncthreads();
    float acc[10];
#pragma unroll
    for (int j = 0; j < 10; ++j) acc[j] = bias[q * 10 + j];
    for (int k = 0; k < 128; ++k) {
        float zk = zs[k * 65 + r];
#pragma unroll
        for (int j = 0; j < 10; ++j)
            acc[j] = fmaf(zk, ws[k * 40 + q * 10 + j], acc[j]);
    }
    int grow = r0 + r;
    if (grow < M) {
        float* op = out + (size_t)grow * 40 + q * 10;
#pragma unroll
        for (int j = 0; j < 10; ++j) op[j] = acc[j];
    }
}

extern "C" void kernel_launch(void* const* d_in, const int* in_sizes, int n_in,
                              void* d_out, int out_size, void* d_ws, size_t ws_size,
                              hipStream_t stream) {
    (void)n_in; (void)out_size; (void)ws_size;
    const float* x    = (const float*)d_in[0];
    const int*   ei   = (const int*)d_in[1];
    const float* W0   = (const float*)d_in[2];
    const float* b0   = (const float*)d_in[3];
    const float* W1   = (const float*)d_in[4];
    const float* b1   = (const float*)d_in[5];
    const float* Wout = (const float*)d_in[6];
    const float* bout = (const float*)d_in[7];
    const float* att0 = (const float*)d_in[8];
    const float* hatts= (const float*)d_in[9];
    const float* atts = (const float*)d_in[10];
    const float* hb   = (const float*)d_in[11];
    float* out = (float*)d_out;

    const int N  = in_sizes[0] / 256;
    const int E  = in_sizes[1] / 2;
    const int E2 = E + N;

    char* p = (char*)d_ws;
    auto carve = [&](size_t bytes) -> char* {
        char* r = p;
        p += (bytes + 255) & ~(size_t)255;
        return r;
    };
    float*    h1     = (float*)carve((size_t)N * HC * 4);
    _Float16* hbufA  = (_Float16*)carve((size_t)N * HC * 2);
    _Float16* hbufB  = (_Float16*)carve((size_t)N * HC * 2);
    float*    zbuf   = (float*)carve((size_t)N * HC * 4);
    _Float16* a_e    = (_Float16*)carve((size_t)E2 * NH * 2);
    float*    dinvb  = (float*)carve((size_t)N * NH * 4);
    int* csr_ptr   = (int*)carve((size_t)(N + 1) * 4);
    int* csr_src   = (int*)carve((size_t)E2 * 4);
    int* cursor    = (int*)carve((size_t)N * 4);
    int* partials  = (int*)carve(1024 * 4);

    float decay[5];
    for (int k = 0; k <= 4; ++k) decay[k] = (float)log(1.0 / (k + 1) + 1.0 + 1e-6);

    // ---- CSR build (by destination col) ----
    hipMemsetAsync(cursor, 0, (size_t)N * 4, stream);
    int eb = (E2 + 255) / 256;
    int nb = (N + 255) / 256;
    count_kernel<<<eb, 256, 0, stream>>>(ei, cursor, E, E2);
    scan1_kernel<<<nb, 256, 0, stream>>>(cursor, csr_ptr, partials, N);
    scan2_kernel<<<1, 256, 0, stream>>>(partials, nb);
    scan3_kernel<<<nb, 256, 0, stream>>>(csr_ptr, partials, N, E2);
    hipMemsetAsync(cursor, 0, (size_t)N * 4, stream);
    fill_kernel<<<eb, 256, 0, stream>>>(ei, csr_ptr, cursor, csr_src, E, E2);

    // ---- MLP (hop-0 attention fused into gemm2 epilogue; h0 emitted fp16) ----
    int gb = (N + 127) / 128;
    mlp_gemm<256, true , false><<<gb, 256, 0, stream>>>(x,  W0, b0, h1, N,
                                                        nullptr, nullptr, nullptr, nullptr);
    mlp_gemm<128, false, true ><<<gb, 256, 0, stream>>>(h1, W1, b1, nullptr, N,
                                                        zbuf, hbufA, att0, hb);

    // ---- hops 1..4 ----
    _Float16* hin  = hbufA;
    _Float16* hout = hbufB;
    int wb = (N + 3) / 4;   // 4 waves (nodes) per 256-thread block
    for (int k = 1; k <= 4; ++k) {
        passA_kernel<<<wb, 256, 0, stream>>>(zbuf, csr_ptr, csr_src,
                                             atts + (size_t)(k - 1) * NH * NC,
                                             decay[k - 1], a_e, dinvb, N);
        passB_kernel<<<wb, 256, 0, stream>>>(hin, zbuf, csr_ptr, csr_src, a_e, dinvb,
                                             hatts + (size_t)(k - 1) * NH * 32,
                                             hb + (size_t)k * NH, decay[k - 1], hout, N,
                                             (k < 4) ? 1 : 0);
        _Float16* t = hin; hin = hout; hout = t;
    }

    // ---- classifier ----
    gout_kernel<<<(N + 63) / 64, 256, 0, stream>>>(zbuf, Wout, bout, out, N);
}

// Round 7
// 720.944 us; speedup vs baseline: 2.2366x; 1.0240x over previous
//
#include <hip/hip_runtime.h>
#include <hip/hip_fp16.h>
#include <math.h>

#define NH 8
#define NC 16
#define HC 128

typedef __attribute__((ext_vector_type(4))) _Float16 half4;

// Fast transcendentals: v_exp_f32 / v_log_f32 hardware paths (~1 ulp).
__device__ __forceinline__ float eluf(float x) { return x > 0.f ? x : __expf(x) - 1.f; }
__device__ __forceinline__ float splusf(float x) { return fmaxf(x, 0.f) + __logf(1.f + __expf(-fabsf(x))); }

// ---------------- CSR build ----------------
__global__ void count_kernel(const int* __restrict__ ei, int* __restrict__ cnt, int E, int E2) {
    int e = blockIdx.x * blockDim.x + threadIdx.x;
    if (e >= E2) return;
    int col = (e < E) ? ei[E + e] : (e - E);
    atomicAdd(&cnt[col], 1);
}

__global__ void scan1_kernel(const int* __restrict__ counts, int* __restrict__ ptr,
                             int* __restrict__ partials, int n) {
    __shared__ int tmp[256];
    int t = threadIdx.x;
    int i = blockIdx.x * 256 + t;
    int v = (i < n) ? counts[i] : 0;
    tmp[t] = v;
    __syncthreads();
    for (int off = 1; off < 256; off <<= 1) {
        int add = (t >= off) ? tmp[t - off] : 0;
        __syncthreads();
        tmp[t] += add;
        __syncthreads();
    }
    if (i < n) ptr[i] = tmp[t] - v;            // block-local exclusive
    if (t == 255) partials[blockIdx.x] = tmp[255];
}

__global__ void scan2_kernel(int* __restrict__ partials, int nb) {
    __shared__ int tmp[256];
    int t = threadIdx.x;
    int v = (t < nb) ? partials[t] : 0;
    tmp[t] = v;
    __syncthreads();
    for (int off = 1; off < 256; off <<= 1) {
        int add = (t >= off) ? tmp[t - off] : 0;
        __syncthreads();
        tmp[t] += add;
        __syncthreads();
    }
    if (t < nb) partials[t] = tmp[t] - v;      // exclusive
}

__global__ void scan3_kernel(int* __restrict__ ptr, const int* __restrict__ partials,
                             int n, int total) {
    int i = blockIdx.x * 256 + threadIdx.x;
    if (i < n) ptr[i] += partials[blockIdx.x];
    if (i == 0) ptr[n] = total;
}

__global__ void fill_kernel(const int* __restrict__ ei, const int* __restrict__ ptr,
                            int* __restrict__ cursor, int* __restrict__ src, int E, int E2) {
    int e = blockIdx.x * blockDim.x + threadIdx.x;
    if (e >= E2) return;
    int col, row;
    if (e < E) { row = ei[e]; col = ei[E + e]; }
    else       { row = e - E; col = e - E; }
    int pos = ptr[col] + atomicAdd(&cursor[col], 1);
    src[pos] = row;
}

// ---------------- fp32 GEMM: 64-row tiles ----------------
// out[M x 128] = act(A[M x K] @ W[K x 128] + b)
// HOP0: additionally compute hop-0 attention g per (row, head), write
// z = out * g (fp32 + fp16 shadow) and h as fp16.
template<int K, bool ELU_OUT, bool HOP0>
__global__ __launch_bounds__(256)
void mlp_gemm(const float* __restrict__ A, const float* __restrict__ W,
              const float* __restrict__ bias, float* __restrict__ out, int M,
              float* __restrict__ z_out, _Float16* __restrict__ h16_out,
              _Float16* __restrict__ z16_out,
              const float* __restrict__ att0, const float* __restrict__ hb0) {
    __shared__ float As[16][68];    // [k][m], padded
    __shared__ float Ws[16][128];   // [k][n]
    const int tid = threadIdx.x;
    const int m0 = blockIdx.x * 64;
    const int tm = tid >> 4;        // 0..15 -> rows tm*4..tm*4+3
    const int tn = tid & 15;        // 0..15 -> cols tn*8..tn*8+7
    float acc[4][8];
#pragma unroll
    for (int i = 0; i < 4; ++i)
#pragma unroll
        for (int j = 0; j < 8; ++j) acc[i][j] = 0.f;

    const int ra = tid >> 2;            // 0..63 (A tile row)
    const int qa = (tid & 3) * 4;       // k-quad offset
    const int rw = tid >> 4;            // 0..15 (W tile row)
    const int cw = (tid & 15) * 8;      // W col

    for (int k0 = 0; k0 < K; k0 += 16) {
        float4 a = make_float4(0.f, 0.f, 0.f, 0.f);
        int garow = m0 + ra;
        if (garow < M) a = *(const float4*)(A + (size_t)garow * K + k0 + qa);
        const float* wp = W + (size_t)(k0 + rw) * 128 + cw;
        float4 w0 = *(const float4*)(wp);
        float4 w1 = *(const float4*)(wp + 4);
        __syncthreads();
        As[qa + 0][ra] = a.x; As[qa + 1][ra] = a.y;
        As[qa + 2][ra] = a.z; As[qa + 3][ra] = a.w;
        *(float4*)&Ws[rw][cw]     = w0;
        *(float4*)&Ws[rw][cw + 4] = w1;
        __syncthreads();
#pragma unroll
        for (int kk = 0; kk < 16; ++kk) {
            float ar[4], wr[8];
            *(float4*)&ar[0] = *(const float4*)&As[kk][tm * 4];
            *(float4*)&wr[0] = *(const float4*)&Ws[kk][tn * 8];
            *(float4*)&wr[4] = *(const float4*)&Ws[kk][tn * 8 + 4];
#pragma unroll
            for (int i = 0; i < 4; ++i)
#pragma unroll
                for (int j = 0; j < 8; ++j)
                    acc[i][j] = fmaf(ar[i], wr[j], acc[i][j]);
        }
    }
#pragma unroll
    for (int i = 0; i < 4; ++i) {
        int r = m0 + tm * 4 + i;
        float vv[8];
#pragma unroll
        for (int j = 0; j < 8; ++j) {
            float v = acc[i][j] + bias[tn * 8 + j];
            if (ELU_OUT) v = eluf(v);
            vv[j] = v;
        }
        if (HOP0) {
            // g[r][hd] = hb0[hd] + sum_c att0[hd*16+c]*elu(h[r][c]);
            // cols tn*8..tn*8+7 are att0-flat; partner lane^1 has the other 8.
            float part = 0.f;
#pragma unroll
            for (int j = 0; j < 8; ++j)
                part += att0[tn * 8 + j] * eluf(vv[j]);
            part += __shfl_xor(part, 1);
            float g = part + hb0[tn >> 1];
            if (r < M) {
                _Float16* hp = h16_out + (size_t)r * 128 + tn * 8;
                _Float16* zhp = z16_out + (size_t)r * 128 + tn * 8;
                float* zp = z_out + (size_t)r * 128 + tn * 8;
                half4 h0, h1, zh0, zh1;
                h0.x = (_Float16)vv[0]; h0.y = (_Float16)vv[1];
                h0.z = (_Float16)vv[2]; h0.w = (_Float16)vv[3];
                h1.x = (_Float16)vv[4]; h1.y = (_Float16)vv[5];
                h1.z = (_Float16)vv[6]; h1.w = (_Float16)vv[7];
                *(half4*)(hp)     = h0;
                *(half4*)(hp + 4) = h1;
                float zz[8];
#pragma unroll
                for (int j = 0; j < 8; ++j) zz[j] = vv[j] * g;
                zh0.x = (_Float16)zz[0]; zh0.y = (_Float16)zz[1];
                zh0.z = (_Float16)zz[2]; zh0.w = (_Float16)zz[3];
                zh1.x = (_Float16)zz[4]; zh1.y = (_Float16)zz[5];
                zh1.z = (_Float16)zz[6]; zh1.w = (_Float16)zz[7];
                *(half4*)(zhp)     = zh0;
                *(half4*)(zhp + 4) = zh1;
#pragma unroll
                for (int j = 0; j < 8; ++j) zp[j] = zz[j];
            }
        } else {
            if (r < M) {
                float* op = out + (size_t)r * 128 + tn * 8;
#pragma unroll
                for (int j = 0; j < 8; ++j) op[j] = vv[j];
            }
        }
    }
}

// ---------------- pass A: edge attention + degree + dinv (fused) ----------------
// One wave per node; 2 edges in flight (one per 32-lane half) x unroll-4.
// Lane = (half, q): q covers channels 4q..4q+3; head = q>>2.
// z gathered from fp16 shadow (halves gather traffic); a_e stored fp16.
__global__ __launch_bounds__(256)
void passA_kernel(const _Float16* __restrict__ z16, const int* __restrict__ ptr,
                  const int* __restrict__ src, const float* __restrict__ att,
                  float decay, _Float16* __restrict__ a_e, float* __restrict__ dinv, int n) {
    int wid = (int)((blockIdx.x * 256u + threadIdx.x) >> 6);
    if (wid >= n) return;
    const int lane = threadIdx.x & 63;
    const int half = lane >> 5;       // which of 2 concurrent edges
    const int q    = lane & 31;       // channel quad
    const int hd   = q >> 2;          // head
    const unsigned i = (unsigned)wid;

    const half4 ziH = *(const half4*)(z16 + (i << 7) + (q << 2));
    float4 zi;
    zi.x = (float)ziH.x * decay; zi.y = (float)ziH.y * decay;
    zi.z = (float)ziH.z * decay; zi.w = (float)ziH.w * decay;
    const float4 av = *(const float4*)(att + (q << 2));

    int s0 = ptr[wid], s1 = ptr[wid + 1];
    float dacc = 0.f;
    int s = s0 + half;
    for (; s + 6 < s1; s += 8) {
        unsigned j0 = (unsigned)src[s];
        unsigned j1 = (unsigned)src[s + 2];
        unsigned j2 = (unsigned)src[s + 4];
        unsigned j3 = (unsigned)src[s + 6];
        const half4 r0 = *(const half4*)(z16 + (j0 << 7) + (q << 2));
        const half4 r1 = *(const half4*)(z16 + (j1 << 7) + (q << 2));
        const half4 r2 = *(const half4*)(z16 + (j2 << 7) + (q << 2));
        const half4 r3 = *(const half4*)(z16 + (j3 << 7) + (q << 2));
        float p0, p1, p2, p3;
        p0  = av.x * eluf(fmaf((float)r0.x, decay, zi.x));
        p0 += av.y * eluf(fmaf((float)r0.y, decay, zi.y));
        p0 += av.z * eluf(fmaf((float)r0.z, decay, zi.z));
        p0 += av.w * eluf(fmaf((float)r0.w, decay, zi.w));
        p1  = av.x * eluf(fmaf((float)r1.x, decay, zi.x));
        p1 += av.y * eluf(fmaf((float)r1.y, decay, zi.y));
        p1 += av.z * eluf(fmaf((float)r1.z, decay, zi.z));
        p1 += av.w * eluf(fmaf((float)r1.w, decay, zi.w));
        p2  = av.x * eluf(fmaf((float)r2.x, decay, zi.x));
        p2 += av.y * eluf(fmaf((float)r2.y, decay, zi.y));
        p2 += av.z * eluf(fmaf((float)r2.z, decay, zi.z));
        p2 += av.w * eluf(fmaf((float)r2.w, decay, zi.w));
        p3  = av.x * eluf(fmaf((float)r3.x, decay, zi.x));
        p3 += av.y * eluf(fmaf((float)r3.y, decay, zi.y));
        p3 += av.z * eluf(fmaf((float)r3.z, decay, zi.z));
        p3 += av.w * eluf(fmaf((float)r3.w, decay, zi.w));
        p0 += __shfl_xor(p0, 1); p1 += __shfl_xor(p1, 1);
        p2 += __shfl_xor(p2, 1); p3 += __shfl_xor(p3, 1);
        p0 += __shfl_xor(p0, 2); p1 += __shfl_xor(p1, 2);
        p2 += __shfl_xor(p2, 2); p3 += __shfl_xor(p3, 2);
        if ((q & 3) == 0) {
            float a0 = splusf(p0) + 1e-6f;
            float a1 = splusf(p1) + 1e-6f;
            float a2 = splusf(p2) + 1e-6f;
            float a3 = splusf(p3) + 1e-6f;
            a_e[((unsigned)s << 3) + hd] = (_Float16)a0;
            a_e[((unsigned)(s + 2) << 3) + hd] = (_Float16)a1;
            a_e[((unsigned)(s + 4) << 3) + hd] = (_Float16)a2;
            a_e[((unsigned)(s + 6) << 3) + hd] = (_Float16)a3;
            dacc += (a0 + a1) + (a2 + a3);
        }
    }
    for (; s < s1; s += 2) {
        unsigned j = (unsigned)src[s];
        const half4 r = *(const half4*)(z16 + (j << 7) + (q << 2));
        float p;
        p  = av.x * eluf(fmaf((float)r.x, decay, zi.x));
        p += av.y * eluf(fmaf((float)r.y, decay, zi.y));
        p += av.z * eluf(fmaf((float)r.z, decay, zi.z));
        p += av.w * eluf(fmaf((float)r.w, decay, zi.w));
        p += __shfl_xor(p, 1);
        p += __shfl_xor(p, 2);
        if ((q & 3) == 0) {
            float aval = splusf(p) + 1e-6f;
            a_e[((unsigned)s << 3) + hd] = (_Float16)aval;
            dacc += aval;
        }
    }
    dacc += __shfl_xor(dacc, 32);
    if (half == 0 && (q & 3) == 0) {
        dinv[(i << 3) + hd] = (dacc > 0.f) ? (1.f / sqrtf(dacc)) : 0.f;
    }
}

// ---------------- pass B: propagate + hop attention + z update ----------------
// Same half-wave layout: 2 edges in flight x unroll-4. h gathered/stored fp16.
// z updated fp32; fp16 shadow written for next hop's passA (skip on last hop).
__global__ __launch_bounds__(256)
void passB_kernel(const _Float16* __restrict__ h_in, float* __restrict__ z,
                  _Float16* __restrict__ z16,
                  const int* __restrict__ ptr, const int* __restrict__ src,
                  const _Float16* __restrict__ a_e, const float* __restrict__ dinv,
                  const float* __restrict__ hatt, const float* __restrict__ hb,
                  float decay, _Float16* __restrict__ h_out, int n, int store_h) {
    int wid = (int)((blockIdx.x * 256u + threadIdx.x) >> 6);
    if (wid >= n) return;
    const int lane = threadIdx.x & 63;
    const int half = lane >> 5;
    const int q    = lane & 31;
    const int hd   = q >> 2;
    const unsigned i = (unsigned)wid;

    const float di = dinv[(i << 3) + hd];
    int s0 = ptr[wid], s1 = ptr[wid + 1];
    float ax = 0.f, ay = 0.f, az = 0.f, aw = 0.f;
    int s = s0 + half;
    for (; s + 6 < s1; s += 8) {
        unsigned j0 = (unsigned)src[s];
        unsigned j1 = (unsigned)src[s + 2];
        unsigned j2 = (unsigned)src[s + 4];
        unsigned j3 = (unsigned)src[s + 6];
        float w0 = (float)a_e[((unsigned)s << 3) + hd]       * dinv[(j0 << 3) + hd];
        float w1 = (float)a_e[((unsigned)(s + 2) << 3) + hd] * dinv[(j1 << 3) + hd];
        float w2 = (float)a_e[((unsigned)(s + 4) << 3) + hd] * dinv[(j2 << 3) + hd];
        float w3 = (float)a_e[((unsigned)(s + 6) << 3) + hd] * dinv[(j3 << 3) + hd];
        const half4 f0 = *(const half4*)(h_in + (j0 << 7) + (q << 2));
        const half4 f1 = *(const half4*)(h_in + (j1 << 7) + (q << 2));
        const half4 f2 = *(const half4*)(h_in + (j2 << 7) + (q << 2));
        const half4 f3 = *(const half4*)(h_in + (j3 << 7) + (q << 2));
        ax = fmaf(w0, (float)f0.x, ax); ay = fmaf(w0, (float)f0.y, ay);
        az = fmaf(w0, (float)f0.z, az); aw = fmaf(w0, (float)f0.w, aw);
        ax = fmaf(w1, (float)f1.x, ax); ay = fmaf(w1, (float)f1.y, ay);
        az = fmaf(w1, (float)f1.z, az); aw = fmaf(w1, (float)f1.w, aw);
        ax = fmaf(w2, (float)f2.x, ax); ay = fmaf(w2, (float)f2.y, ay);
        az = fmaf(w2, (float)f2.z, az); aw = fmaf(w2, (float)f2.w, aw);
        ax = fmaf(w3, (float)f3.x, ax); ay = fmaf(w3, (float)f3.y, ay);
        az = fmaf(w3, (float)f3.z, az); aw = fmaf(w3, (float)f3.w, aw);
    }
    for (; s < s1; s += 2) {
        unsigned j = (unsigned)src[s];
        float w = (float)a_e[((unsigned)s << 3) + hd] * dinv[(j << 3) + hd];
        const half4 f = *(const half4*)(h_in + (j << 7) + (q << 2));
        ax = fmaf(w, (float)f.x, ax); ay = fmaf(w, (float)f.y, ay);
        az = fmaf(w, (float)f.z, az); aw = fmaf(w, (float)f.w, aw);
    }
    // combine the two halves (each accumulated a disjoint set of edges)
    ax += __shfl_xor(ax, 32);
    ay += __shfl_xor(ay, 32);
    az += __shfl_xor(az, 32);
    aw += __shfl_xor(aw, 32);

    const float4 hn = make_float4(di * ax, di * ay, di * az, di * aw);
    const float4 zv = *(const float4*)(z + (i << 7) + (q << 2));
    const float* hA = hatt + hd * 32 + ((q & 3) << 2);
    float p;
    p  = hA[0] * eluf(hn.x) + hA[1] * eluf(hn.y)
       + hA[2] * eluf(hn.z) + hA[3] * eluf(hn.w);
    p += hA[16] * eluf(zv.x * decay) + hA[17] * eluf(zv.y * decay)
       + hA[18] * eluf(zv.z * decay) + hA[19] * eluf(zv.w * decay);
    p += __shfl_xor(p, 1);
    p += __shfl_xor(p, 2);
    const float g = p + hb[hd];
    if (half == 0) {
        float4 zn = make_float4(zv.x + hn.x * g, zv.y + hn.y * g,
                                zv.z + hn.z * g, zv.w + hn.w * g);
        if (store_h) {
            half4 ho, zo;
            ho.x = (_Float16)hn.x; ho.y = (_Float16)hn.y;
            ho.z = (_Float16)hn.z; ho.w = (_Float16)hn.w;
            *(half4*)(h_out + (i << 7) + (q << 2)) = ho;
            zo.x = (_Float16)zn.x; zo.y = (_Float16)zn.y;
            zo.z = (_Float16)zn.z; zo.w = (_Float16)zn.w;
            *(half4*)(z16 + (i << 7) + (q << 2)) = zo;
        }
        *(float4*)(z + (i << 7) + (q << 2)) = zn;
    }
}

// ---------------- output GEMM: out[M x 40] = elu(z)[M x 128] @ Wout + bout --------------
__global__ __launch_bounds__(256)
void gout_kernel(const float* __restrict__ z, const float* __restrict__ W,
                 const float* __restrict__ bias, float* __restrict__ out, int M) {
    __shared__ float zs[128 * 65];   // [k][r], stride 65
    __shared__ float ws[128 * 40];   // [k][n]
    const int tid = threadIdx.x;
    const int r0 = blockIdx.x * 64;
    for (int idx = tid; idx < 128 * 40; idx += 256) ws[idx] = W[idx];
    const int r = tid >> 2;   // 0..63
    const int q = tid & 3;    // 0..3
    {
        int grow = r0 + r;
#pragma unroll
        for (int t = 0; t < 8; ++t) {
            int k = q * 4 + t * 16;
            float4 v = make_float4(0.f, 0.f, 0.f, 0.f);
            if (grow < M) v = *(const float4*)(z + (size_t)grow * HC + k);
            zs[(k + 0) * 65 + r] = eluf(v.x);
            zs[(k + 1) * 65 + r] = eluf(v.y);
            zs[(k + 2) * 65 + r] = eluf(v.z);
            zs[(k + 3) * 65 + r] = eluf(v.w);
        }
    }
    __syncthreads();
    float acc[10];
#pragma unroll
    for (int j = 0; j < 10; ++j) acc[j] = bias[q * 10 + j];
    for (int k = 0; k < 128; ++k) {
        float zk = zs[k * 65 + r];
#pragma unroll
        for (int j = 0; j < 10; ++j)
            acc[j] = fmaf(zk, ws[k * 40 + q * 10 + j], acc[j]);
    }
    int grow = r0 + r;
    if (grow < M) {
        float* op = out + (size_t)grow * 40 + q * 10;
#pragma unroll
        for (int j = 0; j < 10; ++j) op[j] = acc[j];
    }
}

extern "C" void kernel_launch(void* const* d_in, const int* in_sizes, int n_in,
                              void* d_out, int out_size, void* d_ws, size_t ws_size,
                              hipStream_t stream) {
    (void)n_in; (void)out_size; (void)ws_size;
    const float* x    = (const float*)d_in[0];
    const int*   ei   = (const int*)d_in[1];
    const float* W0   = (const float*)d_in[2];
    const float* b0   = (const float*)d_in[3];
    const float* W1   = (const float*)d_in[4];
    const float* b1   = (const float*)d_in[5];
    const float* Wout = (const float*)d_in[6];
    const float* bout = (const float*)d_in[7];
    const float* att0 = (const float*)d_in[8];
    const float* hatts= (const float*)d_in[9];
    const float* atts = (const float*)d_in[10];
    const float* hb   = (const float*)d_in[11];
    float* out = (float*)d_out;

    const int N  = in_sizes[0] / 256;
    const int E  = in_sizes[1] / 2;
    const int E2 = E + N;

    char* p = (char*)d_ws;
    auto carve = [&](size_t bytes) -> char* {
        char* r = p;
        p += (bytes + 255) & ~(size_t)255;
        return r;
    };
    float*    h1     = (float*)carve((size_t)N * HC * 4);
    _Float16* hbufA  = (_Float16*)carve((size_t)N * HC * 2);
    _Float16* hbufB  = (_Float16*)carve((size_t)N * HC * 2);
    float*    zbuf   = (float*)carve((size_t)N * HC * 4);
    _Float16* z16buf = (_Float16*)carve((size_t)N * HC * 2);
    _Float16* a_e    = (_Float16*)carve((size_t)E2 * NH * 2);
    float*    dinvb  = (float*)carve((size_t)N * NH * 4);
    int* csr_ptr   = (int*)carve((size_t)(N + 1) * 4);
    int* csr_src   = (int*)carve((size_t)E2 * 4);
    int* cursor    = (int*)carve((size_t)N * 4);
    int* partials  = (int*)carve(1024 * 4);

    float decay[5];
    for (int k = 0; k <= 4; ++k) decay[k] = (float)log(1.0 / (k + 1) + 1.0 + 1e-6);

    // ---- CSR build (by destination col) ----
    hipMemsetAsync(cursor, 0, (size_t)N * 4, stream);
    int eb = (E2 + 255) / 256;
    int nb = (N + 255) / 256;
    count_kernel<<<eb, 256, 0, stream>>>(ei, cursor, E, E2);
    scan1_kernel<<<nb, 256, 0, stream>>>(cursor, csr_ptr, partials, N);
    scan2_kernel<<<1, 256, 0, stream>>>(partials, nb);
    scan3_kernel<<<nb, 256, 0, stream>>>(csr_ptr, partials, N, E2);
    hipMemsetAsync(cursor, 0, (size_t)N * 4, stream);
    fill_kernel<<<eb, 256, 0, stream>>>(ei, csr_ptr, cursor, csr_src, E, E2);

    // ---- MLP (hop-0 attention fused into gemm2 epilogue; h0/z0 fp16 shadows) ----
    int gb = (N + 63) / 64;
    mlp_gemm<256, true , false><<<gb, 256, 0, stream>>>(x,  W0, b0, h1, N,
                                                        nullptr, nullptr, nullptr,
                                                        nullptr, nullptr);
    mlp_gemm<128, false, true ><<<gb, 256, 0, stream>>>(h1, W1, b1, nullptr, N,
                                                        zbuf, hbufA, z16buf, att0, hb);

    // ---- hops 1..4 ----
    _Float16* hin  = hbufA;
    _Float16* hout = hbufB;
    int wb = (N + 3) / 4;   // 4 waves (nodes) per 256-thread block
    for (int k = 1; k <= 4; ++k) {
        passA_kernel<<<wb, 256, 0, stream>>>(z16buf, csr_ptr, csr_src,
                                             atts + (size_t)(k - 1) * NH * NC,
                                             decay[k - 1], a_e, dinvb, N);
        passB_kernel<<<wb, 256, 0, stream>>>(hin, zbuf, z16buf, csr_ptr, csr_src,
                                             a_e, dinvb,
                                             hatts + (size_t)(k - 1) * NH * 32,
                                             hb + (size_t)k * NH, decay[k - 1], hout, N,
                                             (k < 4) ? 1 : 0);
        _Float16* t = hin; hin = hout; hout = t;
    }

    // ---- classifier ----
    gout_kernel<<<(N + 63) / 64, 256, 0, stream>>>(zbuf, Wout, bout, out, N);
}

// Round 9
// 715.521 us; speedup vs baseline: 2.2535x; 1.0076x over previous
//
#include <hip/hip_runtime.h>
#include <hip/hip_fp16.h>
#include <math.h>

#define NH 8
#define NC 16
#define HC 128

typedef __attribute__((ext_vector_type(4))) _Float16 half4;

// Fast transcendentals: v_exp_f32 / v_log_f32 hardware paths (~1 ulp).
__device__ __forceinline__ float eluf(float x) { return x > 0.f ? x : __expf(x) - 1.f; }
__device__ __forceinline__ float splusf(float x) { return fmaxf(x, 0.f) + __logf(1.f + __expf(-fabsf(x))); }

// ---------------- CSR build ----------------
__global__ void count_kernel(const int* __restrict__ ei, int* __restrict__ cnt, int E, int E2) {
    int e = blockIdx.x * blockDim.x + threadIdx.x;
    if (e >= E2) return;
    int col = (e < E) ? ei[E + e] : (e - E);
    atomicAdd(&cnt[col], 1);
}

__global__ void scan1_kernel(const int* __restrict__ counts, int* __restrict__ ptr,
                             int* __restrict__ partials, int n) {
    __shared__ int tmp[256];
    int t = threadIdx.x;
    int i = blockIdx.x * 256 + t;
    int v = (i < n) ? counts[i] : 0;
    tmp[t] = v;
    __syncthreads();
    for (int off = 1; off < 256; off <<= 1) {
        int add = (t >= off) ? tmp[t - off] : 0;
        __syncthreads();
        tmp[t] += add;
        __syncthreads();
    }
    if (i < n) ptr[i] = tmp[t] - v;            // block-local exclusive
    if (t == 255) partials[blockIdx.x] = tmp[255];
}

__global__ void scan2_kernel(int* __restrict__ partials, int nb) {
    __shared__ int tmp[256];
    int t = threadIdx.x;
    int v = (t < nb) ? partials[t] : 0;
    tmp[t] = v;
    __syncthreads();
    for (int off = 1; off < 256; off <<= 1) {
        int add = (t >= off) ? tmp[t - off] : 0;
        __syncthreads();
        tmp[t] += add;
        __syncthreads();
    }
    if (t < nb) partials[t] = tmp[t] - v;      // exclusive
}

__global__ void scan3_kernel(int* __restrict__ ptr, const int* __restrict__ partials,
                             int n, int total) {
    int i = blockIdx.x * 256 + threadIdx.x;
    if (i < n) ptr[i] += partials[blockIdx.x];
    if (i == 0) ptr[n] = total;
}

__global__ void fill_kernel(const int* __restrict__ ei, const int* __restrict__ ptr,
                            int* __restrict__ cursor, int* __restrict__ src, int E, int E2) {
    int e = blockIdx.x * blockDim.x + threadIdx.x;
    if (e >= E2) return;
    int col, row;
    if (e < E) { row = ei[e]; col = ei[E + e]; }
    else       { row = e - E; col = e - E; }
    int pos = ptr[col] + atomicAdd(&cursor[col], 1);
    src[pos] = row;
}

// ---------------- fp32 GEMM: 64-row tiles, 2-way column split ----------------
// out[M x 128] = act(A[M x K] @ W[K x 128] + b)
// Thread (tm=tid>>4, tn=tid&15): rows tm*4..+3, cols {c*64 + tn*4 + j, c=0..1, j=0..3}
// (covers 0..127 exactly once). Ws stride 132; float4 reads at 16 B lane stride
// => banks {0,4,..,28}, 2-way aliasing only (free).
// HOP0: fused hop-0 attention; head of cols c*64+tn*4.. = 4c + (tn>>2);
// the tn&3 quad covers the head's 16 channels, reduced via shfl_xor(1,2).
template<int K, bool ELU_OUT, bool HOP0>
__global__ __launch_bounds__(256)
void mlp_gemm(const float* __restrict__ A, const float* __restrict__ W,
              const float* __restrict__ bias, float* __restrict__ out, int M,
              float* __restrict__ z_out, _Float16* __restrict__ h16_out,
              _Float16* __restrict__ z16_out,
              const float* __restrict__ att0, const float* __restrict__ hb0) {
    __shared__ float As[16 * 68];    // [k][m], stride 68
    __shared__ float Ws[16 * 132];   // [k][n], stride 132
    const int tid = threadIdx.x;
    const int m0 = blockIdx.x * 64;
    const int tm = tid >> 4;        // 0..15 -> rows tm*4..tm*4+3
    const int tn = tid & 15;        // cols c*64 + tn*4
    float acc[4][8];
#pragma unroll
    for (int i = 0; i < 4; ++i)
#pragma unroll
        for (int j = 0; j < 8; ++j) acc[i][j] = 0.f;

    const int ra = tid >> 2;            // 0..63 (A tile row)
    const int qa = (tid & 3) * 4;       // k-quad offset

    for (int k0 = 0; k0 < K; k0 += 16) {
        float4 a = make_float4(0.f, 0.f, 0.f, 0.f);
        int garow = m0 + ra;
        if (garow < M) a = *(const float4*)(A + (size_t)garow * K + k0 + qa);
        float wv[8];
#pragma unroll
        for (int t = 0; t < 8; ++t) {
            int idx = tid + t * 256;          // 0..2047
            int r = idx >> 7, c = idx & 127;
            wv[t] = W[(size_t)(k0 + r) * 128 + c];
        }
        __syncthreads();
        As[(qa + 0) * 68 + ra] = a.x; As[(qa + 1) * 68 + ra] = a.y;
        As[(qa + 2) * 68 + ra] = a.z; As[(qa + 3) * 68 + ra] = a.w;
#pragma unroll
        for (int t = 0; t < 8; ++t) {
            int idx = tid + t * 256;
            int r = idx >> 7, c = idx & 127;
            Ws[r * 132 + c] = wv[t];
        }
        __syncthreads();
#pragma unroll
        for (int kk = 0; kk < 16; ++kk) {
            float ar[4], wr[8];
            *(float4*)&ar[0] = *(const float4*)&As[kk * 68 + tm * 4];
            *(float4*)&wr[0] = *(const float4*)&Ws[kk * 132 + tn * 4];
            *(float4*)&wr[4] = *(const float4*)&Ws[kk * 132 + 64 + tn * 4];
#pragma unroll
            for (int i = 0; i < 4; ++i)
#pragma unroll
                for (int j = 0; j < 8; ++j)
                    acc[i][j] = fmaf(ar[i], wr[j], acc[i][j]);
        }
    }
#pragma unroll
    for (int i = 0; i < 4; ++i) {
        int r = m0 + tm * 4 + i;
        float vv[8];
#pragma unroll
        for (int c = 0; c < 2; ++c)
#pragma unroll
            for (int j = 0; j < 4; ++j) {
                float v = acc[i][c * 4 + j] + bias[c * 64 + tn * 4 + j];
                if (ELU_OUT) v = eluf(v);
                vv[c * 4 + j] = v;
            }
        if (HOP0) {
            float part[2];
#pragma unroll
            for (int c = 0; c < 2; ++c) {
                float p = 0.f;
#pragma unroll
                for (int j = 0; j < 4; ++j)
                    p += att0[c * 64 + tn * 4 + j] * eluf(vv[c * 4 + j]);
                p += __shfl_xor(p, 1);
                p += __shfl_xor(p, 2);
                part[c] = p;
            }
            if (r < M) {
#pragma unroll
                for (int c = 0; c < 2; ++c) {
                    float g = part[c] + hb0[4 * c + (tn >> 2)];
                    int coff = c * 64 + tn * 4;
                    _Float16* hp  = h16_out + ((size_t)r << 7) + coff;
                    _Float16* zhp = z16_out + ((size_t)r << 7) + coff;
                    float*    zp  = z_out   + ((size_t)r << 7) + coff;
                    half4 ho, zo;
                    float zz[4];
#pragma unroll
                    for (int j = 0; j < 4; ++j) zz[j] = vv[c * 4 + j] * g;
                    ho.x = (_Float16)vv[c * 4 + 0]; ho.y = (_Float16)vv[c * 4 + 1];
                    ho.z = (_Float16)vv[c * 4 + 2]; ho.w = (_Float16)vv[c * 4 + 3];
                    zo.x = (_Float16)zz[0]; zo.y = (_Float16)zz[1];
                    zo.z = (_Float16)zz[2]; zo.w = (_Float16)zz[3];
                    *(half4*)hp = ho;
                    *(half4*)zhp = zo;
                    *(float4*)zp = make_float4(zz[0], zz[1], zz[2], zz[3]);
                }
            }
        } else {
            if (r < M) {
#pragma unroll
                for (int c = 0; c < 2; ++c) {
                    float* op = out + (size_t)r * 128 + c * 64 + tn * 4;
                    *(float4*)op = make_float4(vv[c * 4 + 0], vv[c * 4 + 1],
                                               vv[c * 4 + 2], vv[c * 4 + 3]);
                }
            }
        }
    }
}

// ---------------- pass A: edge attention + degree + dinv (fused) ----------------
// One wave per node; 2 edges in flight (one per 32-lane half) x unroll-4.
// Lane = (half, q): q covers channels 4q..4q+3; head = q>>2.
// z gathered from fp16 shadow (halves gather traffic); a_e stored fp16.
__global__ __launch_bounds__(256)
void passA_kernel(const _Float16* __restrict__ z16, const int* __restrict__ ptr,
                  const int* __restrict__ src, const float* __restrict__ att,
                  float decay, _Float16* __restrict__ a_e, float* __restrict__ dinv, int n) {
    int wid = (int)((blockIdx.x * 256u + threadIdx.x) >> 6);
    if (wid >= n) return;
    const int lane = threadIdx.x & 63;
    const int half = lane >> 5;       // which of 2 concurrent edges
    const int q    = lane & 31;       // channel quad
    const int hd   = q >> 2;          // head
    const unsigned i = (unsigned)wid;

    const half4 ziH = *(const half4*)(z16 + (i << 7) + (q << 2));
    float4 zi;
    zi.x = (float)ziH.x * decay; zi.y = (float)ziH.y * decay;
    zi.z = (float)ziH.z * decay; zi.w = (float)ziH.w * decay;
    const float4 av = *(const float4*)(att + (q << 2));

    int s0 = ptr[wid], s1 = ptr[wid + 1];
    float dacc = 0.f;
    int s = s0 + half;
    for (; s + 6 < s1; s += 8) {
        unsigned j0 = (unsigned)src[s];
        unsigned j1 = (unsigned)src[s + 2];
        unsigned j2 = (unsigned)src[s + 4];
        unsigned j3 = (unsigned)src[s + 6];
        const half4 r0 = *(const half4*)(z16 + (j0 << 7) + (q << 2));
        const half4 r1 = *(const half4*)(z16 + (j1 << 7) + (q << 2));
        const half4 r2 = *(const half4*)(z16 + (j2 << 7) + (q << 2));
        const half4 r3 = *(const half4*)(z16 + (j3 << 7) + (q << 2));
        float p0, p1, p2, p3;
        p0  = av.x * eluf(fmaf((float)r0.x, decay, zi.x));
        p0 += av.y * eluf(fmaf((float)r0.y, decay, zi.y));
        p0 += av.z * eluf(fmaf((float)r0.z, decay, zi.z));
        p0 += av.w * eluf(fmaf((float)r0.w, decay, zi.w));
        p1  = av.x * eluf(fmaf((float)r1.x, decay, zi.x));
        p1 += av.y * eluf(fmaf((float)r1.y, decay, zi.y));
        p1 += av.z * eluf(fmaf((float)r1.z, decay, zi.z));
        p1 += av.w * eluf(fmaf((float)r1.w, decay, zi.w));
        p2  = av.x * eluf(fmaf((float)r2.x, decay, zi.x));
        p2 += av.y * eluf(fmaf((float)r2.y, decay, zi.y));
        p2 += av.z * eluf(fmaf((float)r2.z, decay, zi.z));
        p2 += av.w * eluf(fmaf((float)r2.w, decay, zi.w));
        p3  = av.x * eluf(fmaf((float)r3.x, decay, zi.x));
        p3 += av.y * eluf(fmaf((float)r3.y, decay, zi.y));
        p3 += av.z * eluf(fmaf((float)r3.z, decay, zi.z));
        p3 += av.w * eluf(fmaf((float)r3.w, decay, zi.w));
        p0 += __shfl_xor(p0, 1); p1 += __shfl_xor(p1, 1);
        p2 += __shfl_xor(p2, 1); p3 += __shfl_xor(p3, 1);
        p0 += __shfl_xor(p0, 2); p1 += __shfl_xor(p1, 2);
        p2 += __shfl_xor(p2, 2); p3 += __shfl_xor(p3, 2);
        if ((q & 3) == 0) {
            float a0 = splusf(p0) + 1e-6f;
            float a1 = splusf(p1) + 1e-6f;
            float a2 = splusf(p2) + 1e-6f;
            float a3 = splusf(p3) + 1e-6f;
            a_e[((unsigned)s << 3) + hd] = (_Float16)a0;
            a_e[((unsigned)(s + 2) << 3) + hd] = (_Float16)a1;
            a_e[((unsigned)(s + 4) << 3) + hd] = (_Float16)a2;
            a_e[((unsigned)(s + 6) << 3) + hd] = (_Float16)a3;
            dacc += (a0 + a1) + (a2 + a3);
        }
    }
    for (; s < s1; s += 2) {
        unsigned j = (unsigned)src[s];
        const half4 r = *(const half4*)(z16 + (j << 7) + (q << 2));
        float p;
        p  = av.x * eluf(fmaf((float)r.x, decay, zi.x));
        p += av.y * eluf(fmaf((float)r.y, decay, zi.y));
        p += av.z * eluf(fmaf((float)r.z, decay, zi.z));
        p += av.w * eluf(fmaf((float)r.w, decay, zi.w));
        p += __shfl_xor(p, 1);
        p += __shfl_xor(p, 2);
        if ((q & 3) == 0) {
            float aval = splusf(p) + 1e-6f;
            a_e[((unsigned)s << 3) + hd] = (_Float16)aval;
            dacc += aval;
        }
    }
    dacc += __shfl_xor(dacc, 32);
    if (half == 0 && (q & 3) == 0) {
        dinv[(i << 3) + hd] = (dacc > 0.f) ? (1.f / sqrtf(dacc)) : 0.f;
    }
}

// ---------------- pass B: propagate + hop attention + z update ----------------
// Same half-wave layout: 2 edges in flight x unroll-4. h gathered/stored fp16.
// z updated fp32; fp16 shadow written for next hop's passA (skip on last hop).
__global__ __launch_bounds__(256)
void passB_kernel(const _Float16* __restrict__ h_in, float* __restrict__ z,
                  _Float16* __restrict__ z16,
                  const int* __restrict__ ptr, const int* __restrict__ src,
                  const _Float16* __restrict__ a_e, const float* __restrict__ dinv,
                  const float* __restrict__ hatt, const float* __restrict__ hb,
                  float decay, _Float16* __restrict__ h_out, int n, int store_h) {
    int wid = (int)((blockIdx.x * 256u + threadIdx.x) >> 6);
    if (wid >= n) return;
    const int lane = threadIdx.x & 63;
    const int half = lane >> 5;
    const int q    = lane & 31;
    const int hd   = q >> 2;
    const unsigned i = (unsigned)wid;

    const float di = dinv[(i << 3) + hd];
    int s0 = ptr[wid], s1 = ptr[wid + 1];
    float ax = 0.f, ay = 0.f, az = 0.f, aw = 0.f;
    int s = s0 + half;
    for (; s + 6 < s1; s += 8) {
        unsigned j0 = (unsigned)src[s];
        unsigned j1 = (unsigned)src[s + 2];
        unsigned j2 = (unsigned)src[s + 4];
        unsigned j3 = (unsigned)src[s + 6];
        float w0 = (float)a_e[((unsigned)s << 3) + hd]       * dinv[(j0 << 3) + hd];
        float w1 = (float)a_e[((unsigned)(s + 2) << 3) + hd] * dinv[(j1 << 3) + hd];
        float w2 = (float)a_e[((unsigned)(s + 4) << 3) + hd] * dinv[(j2 << 3) + hd];
        float w3 = (float)a_e[((unsigned)(s + 6) << 3) + hd] * dinv[(j3 << 3) + hd];
        const half4 f0 = *(const half4*)(h_in + (j0 << 7) + (q << 2));
        const half4 f1 = *(const half4*)(h_in + (j1 << 7) + (q << 2));
        const half4 f2 = *(const half4*)(h_in + (j2 << 7) + (q << 2));
        const half4 f3 = *(const half4*)(h_in + (j3 << 7) + (q << 2));
        ax = fmaf(w0, (float)f0.x, ax); ay = fmaf(w0, (float)f0.y, ay);
        az = fmaf(w0, (float)f0.z, az); aw = fmaf(w0, (float)f0.w, aw);
        ax = fmaf(w1, (float)f1.x, ax); ay = fmaf(w1, (float)f1.y, ay);
        az = fmaf(w1, (float)f1.z, az); aw = fmaf(w1, (float)f1.w, aw);
        ax = fmaf(w2, (float)f2.x, ax); ay = fmaf(w2, (float)f2.y, ay);
        az = fmaf(w2, (float)f2.z, az); aw = fmaf(w2, (float)f2.w, aw);
        ax = fmaf(w3, (float)f3.x, ax); ay = fmaf(w3, (float)f3.y, ay);
        az = fmaf(w3, (float)f3.z, az); aw = fmaf(w3, (float)f3.w, aw);
    }
    for (; s < s1; s += 2) {
        unsigned j = (unsigned)src[s];
        float w = (float)a_e[((unsigned)s << 3) + hd] * dinv[(j << 3) + hd];
        const half4 f = *(const half4*)(h_in + (j << 7) + (q << 2));
        ax = fmaf(w, (float)f.x, ax); ay = fmaf(w, (float)f.y, ay);
        az = fmaf(w, (float)f.z, az); aw = fmaf(w, (float)f.w, aw);
    }
    // combine the two halves (each accumulated a disjoint set of edges)
    ax += __shfl_xor(ax, 32);
    ay += __shfl_xor(ay, 32);
    az += __shfl_xor(az, 32);
    aw += __shfl_xor(aw, 32);

    const float4 hn = make_float4(di * ax, di * ay, di * az, di * aw);
    const float4 zv = *(const float4*)(z + (i << 7) + (q << 2));
    const float* hA = hatt + hd * 32 + ((q & 3) << 2);
    float p;
    p  = hA[0] * eluf(hn.x) + hA[1] * eluf(hn.y)
       + hA[2] * eluf(hn.z) + hA[3] * eluf(hn.w);
    p += hA[16] * eluf(zv.x * decay) + hA[17] * eluf(zv.y * decay)
       + hA[18] * eluf(zv.z * decay) + hA[19] * eluf(zv.w * decay);
    p += __shfl_xor(p, 1);
    p += __shfl_xor(p, 2);
    const float g = p + hb[hd];
    if (half == 0) {
        float4 zn = make_float4(zv.x + hn.x * g, zv.y + hn.y * g,
                                zv.z + hn.z * g, zv.w + hn.w * g);
        if (store_h) {
            half4 ho, zo;
            ho.x = (_Float16)hn.x; ho.y = (_Float16)hn.y;
            ho.z = (_Float16)hn.z; ho.w = (_Float16)hn.w;
            *(half4*)(h_out + (i << 7) + (q << 2)) = ho;
            zo.x = (_Float16)zn.x; zo.y = (_Float16)zn.y;
            zo.z = (_Float16)zn.z; zo.w = (_Float16)zn.w;
            *(half4*)(z16 + (i << 7) + (q << 2)) = zo;
        }
        *(float4*)(z + (i << 7) + (q << 2)) = zn;
    }
}

// ---------------- output GEMM: out[M x 40] = elu(z)[M x 128] @ Wout + bout --------------
__global__ __launch_bounds__(256)
void gout_kernel(const float* __restrict__ z, const float* __restrict__ W,
                 const float* __restrict__ bias, float* __restrict__ out, int M) {
    __shared__ float zs[128 * 65];   // [k][r], stride 65
    __shared__ float ws[128 * 40];   // [k][n]
    const int tid = threadIdx.x;
    const int r0 = blockIdx.x * 64;
    for (int idx = tid; idx < 128 * 40; idx += 256) ws[idx] = W[idx];
    const int r = tid >> 2;   // 0..63
    const int q = tid & 3;    // 0..3
    {
        int grow = r0 + r;
#pragma unroll
        for (int t = 0; t < 8; ++t) {
            int k = q * 4 + t * 16;
            float4 v = make_float4(0.f, 0.f, 0.f, 0.f);
            if (grow < M) v = *(const float4*)(z + (size_t)grow * HC + k);
            zs[(k + 0) * 65 + r] = eluf(v.x);
            zs[(k + 1) * 65 + r] = eluf(v.y);
            zs[(k + 2) * 65 + r] = eluf(v.z);
            zs[(k + 3) * 65 + r] = eluf(v.w);
        }
    }
    __syncthreads();
    float acc[10];
#pragma unroll
    for (int j = 0; j < 10; ++j) acc[j] = bias[q * 10 + j];
    for (int k = 0; k < 128; ++k) {
        float zk = zs[k * 65 + r];
#pragma unroll
        for (int j = 0; j < 10; ++j)
            acc[j] = fmaf(zk, ws[k * 40 + q * 10 + j], acc[j]);
    }
    int grow = r0 + r;
    if (grow < M) {
        float* op = out + (size_t)grow * 40 + q * 10;
#pragma unroll
        for (int j = 0; j < 10; ++j) op[j] = acc[j];
    }
}

extern "C" void kernel_launch(void* const* d_in, const int* in_sizes, int n_in,
                              void* d_out, int out_size, void* d_ws, size_t ws_size,
                              hipStream_t stream) {
    (void)n_in; (void)out_size; (void)ws_size;
    const float* x    = (const float*)d_in[0];
    const int*   ei   = (const int*)d_in[1];
    const float* W0   = (const float*)d_in[2];
    const float* b0   = (const float*)d_in[3];
    const float* W1   = (const float*)d_in[4];
    const float* b1   = (const float*)d_in[5];
    const float* Wout = (const float*)d_in[6];
    const float* bout = (const float*)d_in[7];
    const float* att0 = (const float*)d_in[8];
    const float* hatts= (const float*)d_in[9];
    const float* atts = (const float*)d_in[10];
    const float* hb   = (const float*)d_in[11];
    float* out = (float*)d_out;

    const int N  = in_sizes[0] / 256;
    const int E  = in_sizes[1] / 2;
    const int E2 = E + N;

    char* p = (char*)d_ws;
    auto carve = [&](size_t bytes) -> char* {
        char* r = p;
        p += (bytes + 255) & ~(size_t)255;
        return r;
    };
    float*    h1     = (float*)carve((size_t)N * HC * 4);
    _Float16* hbufA  = (_Float16*)carve((size_t)N * HC * 2);
    _Float16* hbufB  = (_Float16*)carve((size_t)N * HC * 2);
    float*    zbuf   = (float*)carve((size_t)N * HC * 4);
    _Float16* z16buf = (_Float16*)carve((size_t)N * HC * 2);
    _Float16* a_e    = (_Float16*)carve((size_t)E2 * NH * 2);
    float*    dinvb  = (float*)carve((size_t)N * NH * 4);
    int* csr_ptr   = (int*)carve((size_t)(N + 1) * 4);
    int* csr_src   = (int*)carve((size_t)E2 * 4);
    int* cursor    = (int*)carve((size_t)N * 4);
    int* partials  = (int*)carve(1024 * 4);

    float decay[5];
    for (int k = 0; k <= 4; ++k) decay[k] = (float)log(1.0 / (k + 1) + 1.0 + 1e-6);

    // ---- CSR build (by destination col) ----
    hipMemsetAsync(cursor, 0, (size_t)N * 4, stream);
    int eb = (E2 + 255) / 256;
    int nb = (N + 255) / 256;
    count_kernel<<<eb, 256, 0, stream>>>(ei, cursor, E, E2);
    scan1_kernel<<<nb, 256, 0, stream>>>(cursor, csr_ptr, partials, N);
    scan2_kernel<<<1, 256, 0, stream>>>(partials, nb);
    scan3_kernel<<<nb, 256, 0, stream>>>(csr_ptr, partials, N, E2);
    hipMemsetAsync(cursor, 0, (size_t)N * 4, stream);
    fill_kernel<<<eb, 256, 0, stream>>>(ei, csr_ptr, cursor, csr_src, E, E2);

    // ---- MLP (hop-0 attention fused into gemm2 epilogue; h0/z0 fp16 shadows) ----
    int gb = (N + 63) / 64;
    mlp_gemm<256, true , false><<<gb, 256, 0, stream>>>(x,  W0, b0, h1, N,
                                                        nullptr, nullptr, nullptr,
                                                        nullptr, nullptr);
    mlp_gemm<128, false, true ><<<gb, 256, 0, stream>>>(h1, W1, b1, nullptr, N,
                                                        zbuf, hbufA, z16buf, att0, hb);

    // ---- hops 1..4 ----
    _Float16* hin  = hbufA;
    _Float16* hout = hbufB;
    int wb = (N + 3) / 4;   // 4 waves (nodes) per 256-thread block
    for (int k = 1; k <= 4; ++k) {
        passA_kernel<<<wb, 256, 0, stream>>>(z16buf, csr_ptr, csr_src,
                                             atts + (size_t)(k - 1) * NH * NC,
                                             decay[k - 1], a_e, dinvb, N);
        passB_kernel<<<wb, 256, 0, stream>>>(hin, zbuf, z16buf, csr_ptr, csr_src,
                                             a_e, dinvb,
                                             hatts + (size_t)(k - 1) * NH * 32,
                                             hb + (size_t)k * NH, decay[k - 1], hout, N,
                                             (k < 4) ? 1 : 0);
        _Float16* t = hin; hin = hout; hout = t;
    }

    // ---- classifier ----
    gout_kernel<<<(N + 63) / 64, 256, 0, stream>>>(zbuf, Wout, bout, out, N);
}